// Round 1
// baseline (680.561 us; speedup 1.0000x reference)
//
#include <hip/hip_runtime.h>
#include <math.h>

#define B_   8
#define NQ_  900
#define D_   256
#define H_   8
#define P_   4
#define BEV_ 200
#define FFN_ 512
#define HD_  32
#define M_   (B_*NQ_)
#define NKPAD 960

typedef __attribute__((ext_vector_type(8))) short short8;
typedef __attribute__((ext_vector_type(4))) float floatx4;

__device__ inline unsigned short f2bf(float f) {
    union { float f; unsigned u; } v; v.f = f;
    unsigned r = v.u + 0x7fffu + ((v.u >> 16) & 1u);
    return (unsigned short)(r >> 16);
}
__device__ inline float bf2f(unsigned short h) {
    union { unsigned u; float f; } v; v.u = ((unsigned)h) << 16;
    return v.f;
}

// ---------------------------------------------------------------------------
// Weight fp32 -> bf16; off_w/wt_w merged into [96,256]; off_b/wt_b -> [96].
// ---------------------------------------------------------------------------
__global__ __launch_bounds__(256)
void convert_weights(const float* __restrict__ in_w, const float* __restrict__ out_w,
                     const float* __restrict__ off_w, const float* __restrict__ wt_w,
                     const float* __restrict__ co_w, const float* __restrict__ f_w1,
                     const float* __restrict__ f_w2, const float* __restrict__ off_b,
                     const float* __restrict__ wt_b,
                     unsigned short* __restrict__ wb, float* __restrict__ bias_ow)
{
    int i = blockIdx.x * 256 + threadIdx.x;
    if (i < 196608)      { wb[i] = f2bf(in_w[i]); }
    else if (i < 262144) { wb[i] = f2bf(out_w[i - 196608]); }
    else if (i < 278528) { wb[i] = f2bf(off_w[i - 262144]); }
    else if (i < 286720) { wb[i] = f2bf(wt_w[i - 278528]); }
    else if (i < 352256) { wb[i] = f2bf(co_w[i - 286720]); }
    else if (i < 483328) { wb[i] = f2bf(f_w1[i - 352256]); }
    else if (i < 614400) { wb[i] = f2bf(f_w2[i - 483328]); }
    else if (i < 614464) { bias_ow[i - 614400] = off_b[i - 614400]; }
    else if (i < 614496) { bias_ow[i - 614400] = wt_b[i - 614464]; }
}

// ---------------------------------------------------------------------------
// LayerNorm over last dim (256); optional pos add; bf16 out.
// ---------------------------------------------------------------------------
__global__ __launch_bounds__(256)
void ln_kernel(const float* __restrict__ x, const float* __restrict__ pos,
               const float* __restrict__ gamma, const float* __restrict__ beta,
               unsigned short* __restrict__ out, int rows)
{
    int w    = threadIdx.x >> 6;
    int lane = threadIdx.x & 63;
    int row  = blockIdx.x * 4 + w;
    if (row >= rows) return;
    size_t base = (size_t)row * D_ + lane * 4;
    float4 v = *(const float4*)(x + base);
    if (pos) {
        float4 p = *(const float4*)(pos + base);
        v.x += p.x; v.y += p.y; v.z += p.z; v.w += p.w;
    }
    float s = v.x + v.y + v.z + v.w;
    float q = v.x*v.x + v.y*v.y + v.z*v.z + v.w*v.w;
    #pragma unroll
    for (int o = 1; o < 64; o <<= 1) {
        s += __shfl_xor(s, o, 64);
        q += __shfl_xor(q, o, 64);
    }
    float m   = s * (1.0f / D_);
    float var = q * (1.0f / D_) - m * m;
    float inv = rsqrtf(var + 1e-5f);
    float4 g = *(const float4*)(gamma + lane * 4);
    float4 b = *(const float4*)(beta  + lane * 4);
    ushort4 o4;
    o4.x = f2bf((v.x - m) * inv * g.x + b.x);
    o4.y = f2bf((v.y - m) * inv * g.y + b.y);
    o4.z = f2bf((v.z - m) * inv * g.z + b.z);
    o4.w = f2bf((v.w - m) * inv * g.w + b.w);
    *(ushort4*)(out + base) = o4;
}

// ---------------------------------------------------------------------------
// bf16 MFMA GEMM (unchanged from R2).
// ---------------------------------------------------------------------------
template<int RELU, int OUTBF>
__global__ __launch_bounds__(256)
void gemm_mfma(const unsigned short* __restrict__ A, const unsigned short* __restrict__ W,
               const float* __restrict__ bias, const float* __restrict__ res,
               float* __restrict__ outf, unsigned short* __restrict__ outb,
               int M, int N, int K)
{
    __shared__ unsigned short As[128 * 32];
    __shared__ unsigned short Bs[128 * 32];
    const int t    = threadIdx.x;
    const int m0   = blockIdx.y * 128;
    const int n0   = blockIdx.x * 128;
    const int lane = t & 63;
    const int w    = t >> 6;
    const int wm   = (w >> 1) * 64;
    const int wn   = (w & 1) * 64;
    const int lr   = lane & 15;
    const int kq   = lane >> 4;

    floatx4 acc[4][4];
    #pragma unroll
    for (int i = 0; i < 4; ++i)
        #pragma unroll
        for (int j = 0; j < 4; ++j) acc[i][j] = (floatx4){0.f, 0.f, 0.f, 0.f};

    const int sr = t >> 1;
    const int sc = (t & 1) * 2;

    for (int k0 = 0; k0 < K; k0 += 32) {
        uint4 a0 = {0,0,0,0}, a1 = {0,0,0,0};
        int gm = m0 + sr;
        if (gm < M) {
            const uint4* src = (const uint4*)(A + (size_t)gm * K + k0 + sc * 8);
            a0 = src[0]; a1 = src[1];
        }
        *(uint4*)&As[sr * 32 + ((sc    ) ^ (sr & 3)) * 8] = a0;
        *(uint4*)&As[sr * 32 + ((sc + 1) ^ (sr & 3)) * 8] = a1;
        uint4 b0 = {0,0,0,0}, b1 = {0,0,0,0};
        int gn = n0 + sr;
        if (gn < N) {
            const uint4* src = (const uint4*)(W + (size_t)gn * K + k0 + sc * 8);
            b0 = src[0]; b1 = src[1];
        }
        *(uint4*)&Bs[sr * 32 + ((sc    ) ^ (sr & 3)) * 8] = b0;
        *(uint4*)&Bs[sr * 32 + ((sc + 1) ^ (sr & 3)) * 8] = b1;
        __syncthreads();

        short8 af[4], bfr[4];
        #pragma unroll
        for (int i = 0; i < 4; ++i) {
            int ra = wm + i * 16 + lr;
            af[i] = *(const short8*)&As[ra * 32 + (kq ^ (ra & 3)) * 8];
            int rb = wn + i * 16 + lr;
            bfr[i] = *(const short8*)&Bs[rb * 32 + (kq ^ (rb & 3)) * 8];
        }
        #pragma unroll
        for (int mi = 0; mi < 4; ++mi)
            #pragma unroll
            for (int ni = 0; ni < 4; ++ni)
                acc[mi][ni] = __builtin_amdgcn_mfma_f32_16x16x32_bf16(
                    af[mi], bfr[ni], acc[mi][ni], 0, 0, 0);
        __syncthreads();
    }

    const int rbase = kq * 4;
    #pragma unroll
    for (int ni = 0; ni < 4; ++ni) {
        int n = n0 + wn + ni * 16 + lr;
        if (n >= N) continue;
        float bv = bias[n];
        #pragma unroll
        for (int mi = 0; mi < 4; ++mi) {
            floatx4 c = acc[mi][ni];
            #pragma unroll
            for (int r = 0; r < 4; ++r) {
                int m = m0 + wm + mi * 16 + rbase + r;
                if (m < M) {
                    float vl = c[r] + bv;
                    if (res) vl += res[(size_t)m * N + n];
                    if (RELU) vl = fmaxf(vl, 0.f);
                    if (OUTBF) outb[(size_t)m * N + n] = f2bf(vl);
                    else       outf[(size_t)m * N + n] = vl;
                }
            }
        }
    }
}

// ---------------------------------------------------------------------------
// Repack bf16 qkv [7200,768] into flash layouts:
//   Qb[bh][960][32] (pre-scaled by 1/sqrt(32)), Kb[bh][960][32], Vt[bh][32][960]
// Zero-fill rows >= 900.
// ---------------------------------------------------------------------------
__global__ __launch_bounds__(256)
void repack_qkv(const unsigned short* __restrict__ qkv,
                unsigned short* __restrict__ Qb, unsigned short* __restrict__ Kb,
                unsigned short* __restrict__ Vt)
{
    int tid = blockIdx.x * 256 + threadIdx.x;
    if (tid >= 64 * NKPAD * 32) return;
    int ch  = tid & 31;
    int key = (tid >> 5) % NKPAD;
    int bh  = tid / (NKPAD * 32);
    int b = bh >> 3, h = bh & 7;
    unsigned short qv = 0, kv = 0, vv = 0;
    if (key < NQ_) {
        const unsigned short* row = qkv + ((size_t)(b * NQ_ + key)) * 768 + h * 32 + ch;
        qv = f2bf(bf2f(row[0]) * 0.17677669529663687f);
        kv = row[256];
        vv = row[512];
    }
    size_t qk_idx = (size_t)bh * NKPAD * 32 + key * 32 + ch;
    Qb[qk_idx] = qv;
    Kb[qk_idx] = kv;
    Vt[(size_t)(bh * 32 + ch) * NKPAD + key] = vv;
}

// ---------------------------------------------------------------------------
// Flash self-attention. Grid (15, 64). 4 waves/block; wave owns 16 q-rows.
// Online softmax fully in registers; P transposed via per-wave LDS.
// ---------------------------------------------------------------------------
__global__ __launch_bounds__(256)
void flash_attn(const unsigned short* __restrict__ Qb, const unsigned short* __restrict__ Kb,
                const unsigned short* __restrict__ Vt, unsigned short* __restrict__ out)
{
    __shared__ unsigned short P_lds[4][16][72];
    const int bh   = blockIdx.y;
    const int b    = bh >> 3, h = bh & 7;
    const int q0   = blockIdx.x * 64;
    const int w    = threadIdx.x >> 6;
    const int lane = threadIdx.x & 63;
    const int lr   = lane & 15;
    const int quad = lane >> 4;

    // Q A-fragment: A[m=lr][k=quad*8..+8], loaded once (pre-scaled).
    const short8 qfrag = *(const short8*)(Qb + ((size_t)bh * NKPAD + q0 + w * 16 + lr) * 32 + quad * 8);

    floatx4 O0 = (floatx4){0.f,0.f,0.f,0.f};
    floatx4 O1 = (floatx4){0.f,0.f,0.f,0.f};
    float m_i[4] = {-INFINITY, -INFINITY, -INFINITY, -INFINITY};
    float l_i[4] = {0.f, 0.f, 0.f, 0.f};

    const unsigned short* kbase_p = Kb + (size_t)bh * NKPAD * 32;
    const unsigned short* vbase_p = Vt + (size_t)bh * 32 * NKPAD;

    for (int kt = 0; kt < 15; ++kt) {
        const int kb = kt * 64;
        // --- QK^T: 4 MFMAs -> S[16q x 64keys] ---
        short8 kf[4];
        #pragma unroll
        for (int ni = 0; ni < 4; ++ni)
            kf[ni] = *(const short8*)(kbase_p + (size_t)(kb + ni * 16 + lr) * 32 + quad * 8);
        floatx4 S[4];
        #pragma unroll
        for (int ni = 0; ni < 4; ++ni)
            S[ni] = __builtin_amdgcn_mfma_f32_16x16x32_bf16(
                qfrag, kf[ni], (floatx4){0.f,0.f,0.f,0.f}, 0, 0, 0);
        // --- mask tail keys ---
        if (kt == 14) {
            #pragma unroll
            for (int ni = 0; ni < 4; ++ni) {
                int key = kb + ni * 16 + lr;
                if (key >= NQ_) S[ni] = (floatx4){-1e30f, -1e30f, -1e30f, -1e30f};
            }
        }
        // --- online softmax (row = quad*4 + r for both S and O) ---
        float rowmax[4];
        #pragma unroll
        for (int r = 0; r < 4; ++r)
            rowmax[r] = fmaxf(fmaxf(S[0][r], S[1][r]), fmaxf(S[2][r], S[3][r]));
        #pragma unroll
        for (int off = 1; off < 16; off <<= 1)
            #pragma unroll
            for (int r = 0; r < 4; ++r)
                rowmax[r] = fmaxf(rowmax[r], __shfl_xor(rowmax[r], off, 64));
        float alpha[4], rs[4];
        #pragma unroll
        for (int r = 0; r < 4; ++r) {
            float mnew = fmaxf(m_i[r], rowmax[r]);
            alpha[r] = __expf(m_i[r] - mnew);
            m_i[r] = mnew;
            rs[r] = 0.f;
        }
        #pragma unroll
        for (int ni = 0; ni < 4; ++ni) {
            #pragma unroll
            for (int r = 0; r < 4; ++r) {
                float p = __expf(S[ni][r] - m_i[r]);
                rs[r] += p;
                P_lds[w][quad * 4 + r][ni * 16 + lr] = f2bf(p);
            }
        }
        #pragma unroll
        for (int off = 1; off < 16; off <<= 1)
            #pragma unroll
            for (int r = 0; r < 4; ++r)
                rs[r] += __shfl_xor(rs[r], off, 64);
        #pragma unroll
        for (int r = 0; r < 4; ++r) {
            l_i[r] = alpha[r] * l_i[r] + rs[r];
            O0[r] *= alpha[r];
            O1[r] *= alpha[r];
        }
        // wave-internal LDS RAW: drain ds_writes before ds_reads
        asm volatile("s_waitcnt lgkmcnt(0)" ::: "memory");
        // --- P A-fragments + V^T B-fragments -> PV ---
        short8 pf0 = *(const short8*)&P_lds[w][lr][quad * 8];
        short8 pf1 = *(const short8*)&P_lds[w][lr][32 + quad * 8];
        short8 vf;
        vf = *(const short8*)(vbase_p + (size_t)(lr) * NKPAD + kb + quad * 8);
        O0 = __builtin_amdgcn_mfma_f32_16x16x32_bf16(pf0, vf, O0, 0, 0, 0);
        vf = *(const short8*)(vbase_p + (size_t)(lr) * NKPAD + kb + 32 + quad * 8);
        O0 = __builtin_amdgcn_mfma_f32_16x16x32_bf16(pf1, vf, O0, 0, 0, 0);
        vf = *(const short8*)(vbase_p + (size_t)(16 + lr) * NKPAD + kb + quad * 8);
        O1 = __builtin_amdgcn_mfma_f32_16x16x32_bf16(pf0, vf, O1, 0, 0, 0);
        vf = *(const short8*)(vbase_p + (size_t)(16 + lr) * NKPAD + kb + 32 + quad * 8);
        O1 = __builtin_amdgcn_mfma_f32_16x16x32_bf16(pf1, vf, O1, 0, 0, 0);
        // ensure LDS reads done before next iteration overwrites P
        asm volatile("s_waitcnt lgkmcnt(0)" ::: "memory");
    }
    // --- epilogue: out[b*900+q][h*32+d] ---
    #pragma unroll
    for (int r = 0; r < 4; ++r) {
        int q = q0 + w * 16 + quad * 4 + r;
        if (q < NQ_) {
            float inv = 1.f / l_i[r];
            size_t base = ((size_t)(b * NQ_ + q)) * D_ + h * 32;
            out[base + lr]      = f2bf(O0[r] * inv);
            out[base + 16 + lr] = f2bf(O1[r] * inv);
        }
    }
}

// ---------------------------------------------------------------------------
// Prep: reads merged [7200,96] off|wt rows.
// ---------------------------------------------------------------------------
__global__ __launch_bounds__(256)
void prep_kernel(const float* __restrict__ offwt, const float* __restrict__ refp,
                 float4* __restrict__ sx, float4* __restrict__ sy, float4* __restrict__ sw)
{
    int idx = blockIdx.x * 256 + threadIdx.x;
    if (idx >= B_ * NQ_ * H_) return;
    int h  = idx & 7;
    int bq = idx >> 3;
    const float* orow = offwt + (size_t)bq * 96 + h * 8;
    const float* wrow = offwt + (size_t)bq * 96 + 64 + h * 4;
    float rx = refp[bq * 2 + 0];
    float ry = refp[bq * 2 + 1];
    float gx[4], gy[4], wv[4];
    #pragma unroll
    for (int p = 0; p < 4; ++p) {
        float ox = tanhf(orow[p * 2 + 0]) * 0.2f;
        float oy = tanhf(orow[p * 2 + 1]) * 0.2f;
        gx[p] = (rx + ox) * (float)BEV_ - 0.5f;
        gy[p] = (ry + oy) * (float)BEV_ - 0.5f;
        wv[p] = wrow[p];
    }
    float mx = fmaxf(fmaxf(wv[0], wv[1]), fmaxf(wv[2], wv[3]));
    float e0 = expf(wv[0]-mx), e1 = expf(wv[1]-mx), e2 = expf(wv[2]-mx), e3 = expf(wv[3]-mx);
    float inv = 1.f / (e0 + e1 + e2 + e3);
    sx[idx] = make_float4(gx[0], gx[1], gx[2], gx[3]);
    sy[idx] = make_float4(gy[0], gy[1], gy[2], gy[3]);
    sw[idx] = make_float4(e0*inv, e1*inv, e2*inv, e3*inv);
}

// ---------------------------------------------------------------------------
// Bilinear sampler; bf16 out.
// ---------------------------------------------------------------------------
__global__ __launch_bounds__(256)
void sample_kernel(const float* __restrict__ mem,
                   const float4* __restrict__ sx, const float4* __restrict__ sy,
                   const float4* __restrict__ sw, unsigned short* __restrict__ fused)
{
    int tid = blockIdx.x * 256 + threadIdx.x;
    if (tid >= B_ * NQ_ * H_ * HD_) return;
    int d   = tid & 31;
    int bqh = tid >> 5;
    int h   = bqh & 7;
    int bq  = bqh >> 3;
    int b   = bq / NQ_;
    const float* mb = mem + (size_t)b * (BEV_ * BEV_) * D_ + h * HD_ + d;
    float4 X = sx[bqh], Y = sy[bqh], W = sw[bqh];
    float xs[4] = {X.x, X.y, X.z, X.w};
    float ys[4] = {Y.x, Y.y, Y.z, Y.w};
    float ws[4] = {W.x, W.y, W.z, W.w};
    float acc = 0.f;
    #pragma unroll
    for (int p = 0; p < 4; ++p) {
        float gx = xs[p], gy = ys[p];
        float x0f = floorf(gx), y0f = floorf(gy);
        int x0 = (int)x0f, y0 = (int)y0f;
        float wx1 = gx - x0f, wy1 = gy - y0f;
        float wx0 = 1.f - wx1, wy0 = 1.f - wy1;
        float s = 0.f;
        #pragma unroll
        for (int cy = 0; cy < 2; ++cy) {
            int yy = y0 + cy;
            if (yy < 0 || yy >= BEV_) continue;
            float wyv = cy ? wy1 : wy0;
            #pragma unroll
            for (int cx = 0; cx < 2; ++cx) {
                int xx = x0 + cx;
                if (xx < 0 || xx >= BEV_) continue;
                float wxv = cx ? wx1 : wx0;
                s += wyv * wxv * mb[((size_t)yy * BEV_ + xx) * D_];
            }
        }
        acc += ws[p] * s;
    }
    fused[(size_t)bq * D_ + h * HD_ + d] = f2bf(acc);
}

// ---------------------------------------------------------------------------
extern "C" void kernel_launch(void* const* d_in, const int* in_sizes, int n_in,
                              void* d_out, int out_size, void* d_ws, size_t ws_size,
                              hipStream_t stream) {
    const float* query     = (const float*)d_in[0];
    const float* memory    = (const float*)d_in[1];
    const float* refp      = (const float*)d_in[2];
    const float* query_pos = (const float*)d_in[3];
    const float* in_w  = (const float*)d_in[4];
    const float* in_b  = (const float*)d_in[5];
    const float* out_w = (const float*)d_in[6];
    const float* out_b = (const float*)d_in[7];
    const float* off_w = (const float*)d_in[8];
    const float* off_b = (const float*)d_in[9];
    const float* wt_w  = (const float*)d_in[10];
    const float* wt_b  = (const float*)d_in[11];
    const float* co_w  = (const float*)d_in[12];
    const float* co_b  = (const float*)d_in[13];
    const float* f_w1  = (const float*)d_in[14];
    const float* f_b1  = (const float*)d_in[15];
    const float* f_w2  = (const float*)d_in[16];
    const float* f_b2  = (const float*)d_in[17];
    const float* n1s = (const float*)d_in[18];
    const float* n1b = (const float*)d_in[19];
    const float* n2s = (const float*)d_in[20];
    const float* n2b = (const float*)d_in[21];
    const float* n3s = (const float*)d_in[22];
    const float* n3b = (const float*)d_in[23];
    float* outp = (float*)d_out;

    // workspace layout (bytes)
    char* w = (char*)d_ws;
    unsigned short* wb      = (unsigned short*)w;              // 1,228,800
    float*          bias_ow = (float*)(w + 1228800);           // 384 (pad)
    unsigned short* ln_bf   = (unsigned short*)(w + 1229184);  // 3,686,400
    float*          q1      = (float*)(w + 4915584);           // 7,372,800
    unsigned short* qkv_bf  = (unsigned short*)(w + 12288384); // 11,059,200
    unsigned short* Qb      = (unsigned short*)(w + 23347584); // 3,932,160
    unsigned short* Kb      = (unsigned short*)(w + 27279744); // 3,932,160
    unsigned short* Vt      = (unsigned short*)(w + 31211904); // 3,932,160 -> end 35,144,064
    // overlays on dead qkv_bf region:
    float*          offwt   = (float*)(w + 12288384);          // 2,764,800
    float*          samp    = (float*)(w + 15053184);          // 2,764,800
    unsigned short* fuse_bf = (unsigned short*)(w + 17817984); // 3,686,400
    unsigned short* h1_bf   = (unsigned short*)(w + 12288384); // 7,372,800 (after fuse consumed)
    unsigned short* attn_bf = ln_bf;                           // reuse

    const unsigned short* wb_in  = wb;
    const unsigned short* wb_out = wb + 196608;
    const unsigned short* wb_ow  = wb + 262144;
    const unsigned short* wb_co  = wb + 286720;
    const unsigned short* wb_f1  = wb + 352256;
    const unsigned short* wb_f2  = wb + 483328;

    dim3 blk(256);
    const int M = M_;

    // 0. weights -> bf16
    convert_weights<<<dim3((614496 + 255) / 256), blk, 0, stream>>>(
        in_w, out_w, off_w, wt_w, co_w, f_w1, f_w2, off_b, wt_b, wb, bias_ow);
    // 1. LN1(query + pos) -> bf16
    ln_kernel<<<dim3(M / 4), blk, 0, stream>>>(query, query_pos, n1s, n1b, ln_bf, M);
    // 2. QKV [7200,768] -> bf16
    gemm_mfma<0,1><<<dim3(6, 57), blk, 0, stream>>>(ln_bf, wb_in, in_b, nullptr,
                                                    nullptr, qkv_bf, M, 768, 256);
    // 3. repack into flash layouts
    repack_qkv<<<dim3(64 * NKPAD * 32 / 256), blk, 0, stream>>>(qkv_bf, Qb, Kb, Vt);
    // 4. flash attention -> bf16
    flash_attn<<<dim3(15, 64), blk, 0, stream>>>(Qb, Kb, Vt, attn_bf);
    // 5. out-proj + residual(query) -> q1 fp32
    gemm_mfma<0,0><<<dim3(2, 57), blk, 0, stream>>>(attn_bf, wb_out, out_b, query,
                                                    q1, nullptr, M, 256, 256);
    // 6. LN2(q1 + pos) -> bf16
    ln_kernel<<<dim3(M / 4), blk, 0, stream>>>(q1, query_pos, n2s, n2b, ln_bf, M);
    // 7. merged off|wt projection [7200,96]
    gemm_mfma<0,0><<<dim3(1, 57), blk, 0, stream>>>(ln_bf, wb_ow, bias_ow, nullptr,
                                                    offwt, nullptr, M, 96, 256);
    // 8. sampling coords + P-softmax
    prep_kernel<<<dim3((B_ * NQ_ * H_ + 255) / 256), blk, 0, stream>>>(
        offwt, refp, (float4*)samp, (float4*)samp + 57600, (float4*)samp + 115200);
    // 9. bilinear sample + fuse -> bf16
    sample_kernel<<<dim3(B_ * NQ_ * H_ * HD_ / 256), blk, 0, stream>>>(
        memory, (const float4*)samp, (const float4*)samp + 57600,
        (const float4*)samp + 115200, fuse_bf);
    // 10. co-proj + residual(q1) -> d_out fp32
    gemm_mfma<0,0><<<dim3(2, 57), blk, 0, stream>>>(fuse_bf, wb_co, co_b, q1,
                                                    outp, nullptr, M, 256, 256);
    // 11. LN3(d_out) -> bf16
    ln_kernel<<<dim3(M / 4), blk, 0, stream>>>(outp, nullptr, n3s, n3b, ln_bf, M);
    // 12. FFN1 + ReLU -> bf16 h1
    gemm_mfma<1,1><<<dim3(4, 57), blk, 0, stream>>>(ln_bf, wb_f1, f_b1, nullptr,
                                                    nullptr, h1_bf, M, 512, 256);
    // 13. FFN2 + residual(d_out) -> d_out
    gemm_mfma<0,0><<<dim3(2, 57), blk, 0, stream>>>(h1_bf, wb_f2, f_b2, outp,
                                                    outp, nullptr, M, 256, 512);
}

// Round 2
// 663.663 us; speedup vs baseline: 1.0255x; 1.0255x over previous
//
#include <hip/hip_runtime.h>
#include <math.h>

#define B_   8
#define NQ_  900
#define D_   256
#define H_   8
#define P_   4
#define BEV_ 200
#define FFN_ 512
#define HD_  32
#define M_   (B_*NQ_)
#define NKPAD 960

typedef __attribute__((ext_vector_type(8))) short short8;
typedef __attribute__((ext_vector_type(4))) float floatx4;

__device__ inline unsigned short f2bf(float f) {
    union { float f; unsigned u; } v; v.f = f;
    unsigned r = v.u + 0x7fffu + ((v.u >> 16) & 1u);
    return (unsigned short)(r >> 16);
}
__device__ inline float bf2f(unsigned short h) {
    union { unsigned u; float f; } v; v.u = ((unsigned)h) << 16;
    return v.f;
}

// ---------------------------------------------------------------------------
// Prologue: weights fp32->bf16 (blocks [0,2401)), Qb/Kb pad zero [2401,2881),
// Vt pad zero [2881,3361), LN1(query+pos) [3361,5161).
// Pad zeroing is required: flash_attn multiplies P=0 by V rows for keys
// >= 900; if those were workspace poison (NaN/Inf), 0*NaN = NaN.
// ---------------------------------------------------------------------------
__global__ __launch_bounds__(256)
void prologue(const float* __restrict__ in_w, const float* __restrict__ out_w,
              const float* __restrict__ off_w, const float* __restrict__ wt_w,
              const float* __restrict__ co_w, const float* __restrict__ f_w1,
              const float* __restrict__ f_w2, const float* __restrict__ off_b,
              const float* __restrict__ wt_b,
              unsigned short* __restrict__ wb, float* __restrict__ bias_ow,
              unsigned short* __restrict__ Qb, unsigned short* __restrict__ Kb,
              unsigned short* __restrict__ Vt,
              const float* __restrict__ query, const float* __restrict__ query_pos,
              const float* __restrict__ n1s, const float* __restrict__ n1b,
              unsigned short* __restrict__ ln_out)
{
    const int bx = blockIdx.x;
    const int t  = threadIdx.x;
    if (bx < 2401) {
        int i = bx * 256 + t;
        if (i < 196608)      { wb[i] = f2bf(in_w[i]); }
        else if (i < 262144) { wb[i] = f2bf(out_w[i - 196608]); }
        else if (i < 278528) { wb[i] = f2bf(off_w[i - 262144]); }
        else if (i < 286720) { wb[i] = f2bf(wt_w[i - 278528]); }
        else if (i < 352256) { wb[i] = f2bf(co_w[i - 286720]); }
        else if (i < 483328) { wb[i] = f2bf(f_w1[i - 352256]); }
        else if (i < 614400) { wb[i] = f2bf(f_w2[i - 483328]); }
        else if (i < 614464) { bias_ow[i - 614400] = off_b[i - 614400]; }
        else if (i < 614496) { bias_ow[i - 614400] = wt_b[i - 614464]; }
    } else if (bx < 2881) {
        // Qb/Kb pad rows q in [900,960): 64 bh * 60 * 32 = 122880 elems
        int j  = (bx - 2401) * 256 + t;
        int bh = j / 1920;
        int rem = j - bh * 1920;
        int q  = 900 + (rem >> 5);
        int ch = rem & 31;
        size_t idx = ((size_t)bh * NKPAD + q) * 32 + ch;
        Qb[idx] = 0;
        Kb[idx] = 0;
    } else if (bx < 3361) {
        // Vt pad cols q in [900,960): Vt[bh][ch][q]
        int j  = (bx - 2881) * 256 + t;
        int bh = j / 1920;
        int rem = j - bh * 1920;
        int ch = rem / 60;
        int k  = rem - ch * 60;
        Vt[((size_t)bh * 32 + ch) * NKPAD + 900 + k] = 0;
    } else {
        // LN1 over query+pos: 4 rows/block, 1800 blocks
        int w    = t >> 6;
        int lane = t & 63;
        int row  = (bx - 3361) * 4 + w;
        size_t base = (size_t)row * D_ + lane * 4;
        float4 v = *(const float4*)(query + base);
        float4 p = *(const float4*)(query_pos + base);
        v.x += p.x; v.y += p.y; v.z += p.z; v.w += p.w;
        float s = v.x + v.y + v.z + v.w;
        float q = v.x*v.x + v.y*v.y + v.z*v.z + v.w*v.w;
        #pragma unroll
        for (int o = 1; o < 64; o <<= 1) {
            s += __shfl_xor(s, o, 64);
            q += __shfl_xor(q, o, 64);
        }
        float m   = s * (1.0f / D_);
        float var = q * (1.0f / D_) - m * m;
        float inv = rsqrtf(var + 1e-5f);
        float4 g = *(const float4*)(n1s + lane * 4);
        float4 b = *(const float4*)(n1b + lane * 4);
        ushort4 o4;
        o4.x = f2bf((v.x - m) * inv * g.x + b.x);
        o4.y = f2bf((v.y - m) * inv * g.y + b.y);
        o4.z = f2bf((v.z - m) * inv * g.z + b.z);
        o4.w = f2bf((v.w - m) * inv * g.w + b.w);
        *(ushort4*)(ln_out + base) = o4;
    }
}

// ---------------------------------------------------------------------------
// LayerNorm over last dim (256); optional pos add; bf16 out.
// ---------------------------------------------------------------------------
__global__ __launch_bounds__(256)
void ln_kernel(const float* __restrict__ x, const float* __restrict__ pos,
               const float* __restrict__ gamma, const float* __restrict__ beta,
               unsigned short* __restrict__ out, int rows)
{
    int w    = threadIdx.x >> 6;
    int lane = threadIdx.x & 63;
    int row  = blockIdx.x * 4 + w;
    if (row >= rows) return;
    size_t base = (size_t)row * D_ + lane * 4;
    float4 v = *(const float4*)(x + base);
    if (pos) {
        float4 p = *(const float4*)(pos + base);
        v.x += p.x; v.y += p.y; v.z += p.z; v.w += p.w;
    }
    float s = v.x + v.y + v.z + v.w;
    float q = v.x*v.x + v.y*v.y + v.z*v.z + v.w*v.w;
    #pragma unroll
    for (int o = 1; o < 64; o <<= 1) {
        s += __shfl_xor(s, o, 64);
        q += __shfl_xor(q, o, 64);
    }
    float m   = s * (1.0f / D_);
    float var = q * (1.0f / D_) - m * m;
    float inv = rsqrtf(var + 1e-5f);
    float4 g = *(const float4*)(gamma + lane * 4);
    float4 b = *(const float4*)(beta  + lane * 4);
    ushort4 o4;
    o4.x = f2bf((v.x - m) * inv * g.x + b.x);
    o4.y = f2bf((v.y - m) * inv * g.y + b.y);
    o4.z = f2bf((v.z - m) * inv * g.z + b.z);
    o4.w = f2bf((v.w - m) * inv * g.w + b.w);
    *(ushort4*)(out + base) = o4;
}

// ---------------------------------------------------------------------------
// bf16 MFMA GEMM. QKVOUT=1 routes output directly into flash layouts
// (fused repack): Q scaled by 1/sqrt(32), V transposed.
// ---------------------------------------------------------------------------
template<int RELU, int OUTBF, int QKVOUT>
__global__ __launch_bounds__(256)
void gemm_mfma(const unsigned short* __restrict__ A, const unsigned short* __restrict__ W,
               const float* __restrict__ bias, const float* __restrict__ res,
               float* __restrict__ outf, unsigned short* __restrict__ outb,
               unsigned short* __restrict__ Qb, unsigned short* __restrict__ Kb,
               unsigned short* __restrict__ Vt,
               int M, int N, int K)
{
    __shared__ unsigned short As[128 * 32];
    __shared__ unsigned short Bs[128 * 32];
    const int t    = threadIdx.x;
    const int m0   = blockIdx.y * 128;
    const int n0   = blockIdx.x * 128;
    const int lane = t & 63;
    const int w    = t >> 6;
    const int wm   = (w >> 1) * 64;
    const int wn   = (w & 1) * 64;
    const int lr   = lane & 15;
    const int kq   = lane >> 4;

    floatx4 acc[4][4];
    #pragma unroll
    for (int i = 0; i < 4; ++i)
        #pragma unroll
        for (int j = 0; j < 4; ++j) acc[i][j] = (floatx4){0.f, 0.f, 0.f, 0.f};

    const int sr = t >> 1;
    const int sc = (t & 1) * 2;

    for (int k0 = 0; k0 < K; k0 += 32) {
        uint4 a0 = {0,0,0,0}, a1 = {0,0,0,0};
        int gm = m0 + sr;
        if (gm < M) {
            const uint4* src = (const uint4*)(A + (size_t)gm * K + k0 + sc * 8);
            a0 = src[0]; a1 = src[1];
        }
        *(uint4*)&As[sr * 32 + ((sc    ) ^ (sr & 3)) * 8] = a0;
        *(uint4*)&As[sr * 32 + ((sc + 1) ^ (sr & 3)) * 8] = a1;
        uint4 b0 = {0,0,0,0}, b1 = {0,0,0,0};
        int gn = n0 + sr;
        if (gn < N) {
            const uint4* src = (const uint4*)(W + (size_t)gn * K + k0 + sc * 8);
            b0 = src[0]; b1 = src[1];
        }
        *(uint4*)&Bs[sr * 32 + ((sc    ) ^ (sr & 3)) * 8] = b0;
        *(uint4*)&Bs[sr * 32 + ((sc + 1) ^ (sr & 3)) * 8] = b1;
        __syncthreads();

        short8 af[4], bfr[4];
        #pragma unroll
        for (int i = 0; i < 4; ++i) {
            int ra = wm + i * 16 + lr;
            af[i] = *(const short8*)&As[ra * 32 + (kq ^ (ra & 3)) * 8];
            int rb = wn + i * 16 + lr;
            bfr[i] = *(const short8*)&Bs[rb * 32 + (kq ^ (rb & 3)) * 8];
        }
        #pragma unroll
        for (int mi = 0; mi < 4; ++mi)
            #pragma unroll
            for (int ni = 0; ni < 4; ++ni)
                acc[mi][ni] = __builtin_amdgcn_mfma_f32_16x16x32_bf16(
                    af[mi], bfr[ni], acc[mi][ni], 0, 0, 0);
        __syncthreads();
    }

    const int rbase = kq * 4;
    #pragma unroll
    for (int ni = 0; ni < 4; ++ni) {
        int n = n0 + wn + ni * 16 + lr;
        if (n >= N) continue;
        float bv = bias[n];
        if (QKVOUT) {
            const int type = n >> 8;
            const int hh   = (n >> 5) & 7;
            const int ch   = n & 31;
            #pragma unroll
            for (int mi = 0; mi < 4; ++mi) {
                floatx4 c = acc[mi][ni];
                #pragma unroll
                for (int r = 0; r < 4; ++r) {
                    int m = m0 + wm + mi * 16 + rbase + r;
                    if (m < M) {
                        float vl = c[r] + bv;
                        int bb = m / 900;
                        int qq = m - bb * 900;
                        size_t bh = (size_t)(bb * 8 + hh);
                        if (type == 0)
                            Qb[(bh * NKPAD + qq) * 32 + ch] = f2bf(vl * 0.17677669529663687f);
                        else if (type == 1)
                            Kb[(bh * NKPAD + qq) * 32 + ch] = f2bf(vl);
                        else
                            Vt[(bh * 32 + ch) * NKPAD + qq] = f2bf(vl);
                    }
                }
            }
        } else {
            #pragma unroll
            for (int mi = 0; mi < 4; ++mi) {
                floatx4 c = acc[mi][ni];
                #pragma unroll
                for (int r = 0; r < 4; ++r) {
                    int m = m0 + wm + mi * 16 + rbase + r;
                    if (m < M) {
                        float vl = c[r] + bv;
                        if (res) vl += res[(size_t)m * N + n];
                        if (RELU) vl = fmaxf(vl, 0.f);
                        if (OUTBF) outb[(size_t)m * N + n] = f2bf(vl);
                        else       outf[(size_t)m * N + n] = vl;
                    }
                }
            }
        }
    }
}

// ---------------------------------------------------------------------------
// off|wt GEMM (M=7200, N=96, K=256, grid (1,57)) with fused prep epilogue:
// stage the 128x96 fp32 tile in LDS, then compute tanh offsets, softmax
// weights and sampling coords in the same kernel.
// ---------------------------------------------------------------------------
__global__ __launch_bounds__(256)
void gemm_offwt_prep(const unsigned short* __restrict__ A, const unsigned short* __restrict__ W,
                     const float* __restrict__ bias, const float* __restrict__ refp,
                     float4* __restrict__ sx, float4* __restrict__ sy, float4* __restrict__ sw)
{
    __shared__ unsigned short As[128 * 32];
    __shared__ unsigned short Bs[128 * 32];
    __shared__ float T[128][100];
    const int t    = threadIdx.x;
    const int m0   = blockIdx.y * 128;
    const int lane = t & 63;
    const int w    = t >> 6;
    const int wm   = (w >> 1) * 64;
    const int wn   = (w & 1) * 64;
    const int lr   = lane & 15;
    const int kq   = lane >> 4;
    const int M = M_, N = 96, K = 256;

    floatx4 acc[4][4];
    #pragma unroll
    for (int i = 0; i < 4; ++i)
        #pragma unroll
        for (int j = 0; j < 4; ++j) acc[i][j] = (floatx4){0.f, 0.f, 0.f, 0.f};

    const int sr = t >> 1;
    const int sc = (t & 1) * 2;

    for (int k0 = 0; k0 < K; k0 += 32) {
        uint4 a0 = {0,0,0,0}, a1 = {0,0,0,0};
        int gm = m0 + sr;
        if (gm < M) {
            const uint4* src = (const uint4*)(A + (size_t)gm * K + k0 + sc * 8);
            a0 = src[0]; a1 = src[1];
        }
        *(uint4*)&As[sr * 32 + ((sc    ) ^ (sr & 3)) * 8] = a0;
        *(uint4*)&As[sr * 32 + ((sc + 1) ^ (sr & 3)) * 8] = a1;
        uint4 b0 = {0,0,0,0}, b1 = {0,0,0,0};
        int gn = sr;
        if (gn < N) {
            const uint4* src = (const uint4*)(W + (size_t)gn * K + k0 + sc * 8);
            b0 = src[0]; b1 = src[1];
        }
        *(uint4*)&Bs[sr * 32 + ((sc    ) ^ (sr & 3)) * 8] = b0;
        *(uint4*)&Bs[sr * 32 + ((sc + 1) ^ (sr & 3)) * 8] = b1;
        __syncthreads();

        short8 af[4], bfr[4];
        #pragma unroll
        for (int i = 0; i < 4; ++i) {
            int ra = wm + i * 16 + lr;
            af[i] = *(const short8*)&As[ra * 32 + (kq ^ (ra & 3)) * 8];
            int rb = wn + i * 16 + lr;
            bfr[i] = *(const short8*)&Bs[rb * 32 + (kq ^ (rb & 3)) * 8];
        }
        #pragma unroll
        for (int mi = 0; mi < 4; ++mi)
            #pragma unroll
            for (int ni = 0; ni < 4; ++ni)
                acc[mi][ni] = __builtin_amdgcn_mfma_f32_16x16x32_bf16(
                    af[mi], bfr[ni], acc[mi][ni], 0, 0, 0);
        __syncthreads();
    }

    // stage full 128x96 tile (plus bias) into LDS
    const int rbase = kq * 4;
    #pragma unroll
    for (int ni = 0; ni < 4; ++ni) {
        int n = wn + ni * 16 + lr;
        if (n >= N) continue;
        float bv = bias[n];
        #pragma unroll
        for (int mi = 0; mi < 4; ++mi) {
            floatx4 c = acc[mi][ni];
            #pragma unroll
            for (int r = 0; r < 4; ++r)
                T[wm + mi * 16 + rbase + r][n] = c[r] + bv;
        }
    }
    __syncthreads();

    // prep: 128 rows x 8 heads = 1024 items, 4 per thread
    #pragma unroll
    for (int it = 0; it < 4; ++it) {
        int item = t + it * 256;
        int row  = item >> 3;
        int h    = item & 7;
        int gq   = m0 + row;
        if (gq >= M) continue;
        float rx = refp[gq * 2 + 0];
        float ry = refp[gq * 2 + 1];
        const float* orow = &T[row][h * 8];
        const float* wrow = &T[row][64 + h * 4];
        float gx[4], gy[4], wv[4];
        #pragma unroll
        for (int p = 0; p < 4; ++p) {
            float ox = tanhf(orow[p * 2 + 0]) * 0.2f;
            float oy = tanhf(orow[p * 2 + 1]) * 0.2f;
            gx[p] = (rx + ox) * (float)BEV_ - 0.5f;
            gy[p] = (ry + oy) * (float)BEV_ - 0.5f;
            wv[p] = wrow[p];
        }
        float mx = fmaxf(fmaxf(wv[0], wv[1]), fmaxf(wv[2], wv[3]));
        float e0 = expf(wv[0]-mx), e1 = expf(wv[1]-mx), e2 = expf(wv[2]-mx), e3 = expf(wv[3]-mx);
        float inv = 1.f / (e0 + e1 + e2 + e3);
        int idx = gq * 8 + h;
        sx[idx] = make_float4(gx[0], gx[1], gx[2], gx[3]);
        sy[idx] = make_float4(gy[0], gy[1], gy[2], gy[3]);
        sw[idx] = make_float4(e0*inv, e1*inv, e2*inv, e3*inv);
    }
}

// ---------------------------------------------------------------------------
// Flash self-attention. Grid (15, 64). 4 waves/block; wave owns 16 q-rows.
// ---------------------------------------------------------------------------
__global__ __launch_bounds__(256)
void flash_attn(const unsigned short* __restrict__ Qb, const unsigned short* __restrict__ Kb,
                const unsigned short* __restrict__ Vt, unsigned short* __restrict__ out)
{
    __shared__ unsigned short P_lds[4][16][72];
    const int bh   = blockIdx.y;
    const int b    = bh >> 3, h = bh & 7;
    const int q0   = blockIdx.x * 64;
    const int w    = threadIdx.x >> 6;
    const int lane = threadIdx.x & 63;
    const int lr   = lane & 15;
    const int quad = lane >> 4;

    const short8 qfrag = *(const short8*)(Qb + ((size_t)bh * NKPAD + q0 + w * 16 + lr) * 32 + quad * 8);

    floatx4 O0 = (floatx4){0.f,0.f,0.f,0.f};
    floatx4 O1 = (floatx4){0.f,0.f,0.f,0.f};
    float m_i[4] = {-INFINITY, -INFINITY, -INFINITY, -INFINITY};
    float l_i[4] = {0.f, 0.f, 0.f, 0.f};

    const unsigned short* kbase_p = Kb + (size_t)bh * NKPAD * 32;
    const unsigned short* vbase_p = Vt + (size_t)bh * 32 * NKPAD;

    for (int kt = 0; kt < 15; ++kt) {
        const int kb = kt * 64;
        short8 kf[4];
        #pragma unroll
        for (int ni = 0; ni < 4; ++ni)
            kf[ni] = *(const short8*)(kbase_p + (size_t)(kb + ni * 16 + lr) * 32 + quad * 8);
        floatx4 S[4];
        #pragma unroll
        for (int ni = 0; ni < 4; ++ni)
            S[ni] = __builtin_amdgcn_mfma_f32_16x16x32_bf16(
                qfrag, kf[ni], (floatx4){0.f,0.f,0.f,0.f}, 0, 0, 0);
        if (kt == 14) {
            #pragma unroll
            for (int ni = 0; ni < 4; ++ni) {
                int key = kb + ni * 16 + lr;
                if (key >= NQ_) S[ni] = (floatx4){-1e30f, -1e30f, -1e30f, -1e30f};
            }
        }
        float rowmax[4];
        #pragma unroll
        for (int r = 0; r < 4; ++r)
            rowmax[r] = fmaxf(fmaxf(S[0][r], S[1][r]), fmaxf(S[2][r], S[3][r]));
        #pragma unroll
        for (int off = 1; off < 16; off <<= 1)
            #pragma unroll
            for (int r = 0; r < 4; ++r)
                rowmax[r] = fmaxf(rowmax[r], __shfl_xor(rowmax[r], off, 64));
        float alpha[4], rs[4];
        #pragma unroll
        for (int r = 0; r < 4; ++r) {
            float mnew = fmaxf(m_i[r], rowmax[r]);
            alpha[r] = __expf(m_i[r] - mnew);
            m_i[r] = mnew;
            rs[r] = 0.f;
        }
        #pragma unroll
        for (int ni = 0; ni < 4; ++ni) {
            #pragma unroll
            for (int r = 0; r < 4; ++r) {
                float p = __expf(S[ni][r] - m_i[r]);
                rs[r] += p;
                P_lds[w][quad * 4 + r][ni * 16 + lr] = f2bf(p);
            }
        }
        #pragma unroll
        for (int off = 1; off < 16; off <<= 1)
            #pragma unroll
            for (int r = 0; r < 4; ++r)
                rs[r] += __shfl_xor(rs[r], off, 64);
        #pragma unroll
        for (int r = 0; r < 4; ++r) {
            l_i[r] = alpha[r] * l_i[r] + rs[r];
            O0[r] *= alpha[r];
            O1[r] *= alpha[r];
        }
        asm volatile("s_waitcnt lgkmcnt(0)" ::: "memory");
        short8 pf0 = *(const short8*)&P_lds[w][lr][quad * 8];
        short8 pf1 = *(const short8*)&P_lds[w][lr][32 + quad * 8];
        short8 vf;
        vf = *(const short8*)(vbase_p + (size_t)(lr) * NKPAD + kb + quad * 8);
        O0 = __builtin_amdgcn_mfma_f32_16x16x32_bf16(pf0, vf, O0, 0, 0, 0);
        vf = *(const short8*)(vbase_p + (size_t)(lr) * NKPAD + kb + 32 + quad * 8);
        O0 = __builtin_amdgcn_mfma_f32_16x16x32_bf16(pf1, vf, O0, 0, 0, 0);
        vf = *(const short8*)(vbase_p + (size_t)(16 + lr) * NKPAD + kb + quad * 8);
        O1 = __builtin_amdgcn_mfma_f32_16x16x32_bf16(pf0, vf, O1, 0, 0, 0);
        vf = *(const short8*)(vbase_p + (size_t)(16 + lr) * NKPAD + kb + 32 + quad * 8);
        O1 = __builtin_amdgcn_mfma_f32_16x16x32_bf16(pf1, vf, O1, 0, 0, 0);
        asm volatile("s_waitcnt lgkmcnt(0)" ::: "memory");
    }
    #pragma unroll
    for (int r = 0; r < 4; ++r) {
        int q = q0 + w * 16 + quad * 4 + r;
        if (q < NQ_) {
            float inv = 1.f / l_i[r];
            size_t base = ((size_t)(b * NQ_ + q)) * D_ + h * 32;
            out[base + lr]      = f2bf(O0[r] * inv);
            out[base + 16 + lr] = f2bf(O1[r] * inv);
        }
    }
}

// ---------------------------------------------------------------------------
// Bilinear sampler; bf16 out.
// ---------------------------------------------------------------------------
__global__ __launch_bounds__(256)
void sample_kernel(const float* __restrict__ mem,
                   const float4* __restrict__ sx, const float4* __restrict__ sy,
                   const float4* __restrict__ sw, unsigned short* __restrict__ fused)
{
    int tid = blockIdx.x * 256 + threadIdx.x;
    if (tid >= B_ * NQ_ * H_ * HD_) return;
    int d   = tid & 31;
    int bqh = tid >> 5;
    int h   = bqh & 7;
    int bq  = bqh >> 3;
    int b   = bq / NQ_;
    const float* mb = mem + (size_t)b * (BEV_ * BEV_) * D_ + h * HD_ + d;
    float4 X = sx[bqh], Y = sy[bqh], W = sw[bqh];
    float xs[4] = {X.x, X.y, X.z, X.w};
    float ys[4] = {Y.x, Y.y, Y.z, Y.w};
    float ws[4] = {W.x, W.y, W.z, W.w};
    float acc = 0.f;
    #pragma unroll
    for (int p = 0; p < 4; ++p) {
        float gx = xs[p], gy = ys[p];
        float x0f = floorf(gx), y0f = floorf(gy);
        int x0 = (int)x0f, y0 = (int)y0f;
        float wx1 = gx - x0f, wy1 = gy - y0f;
        float wx0 = 1.f - wx1, wy0 = 1.f - wy1;
        float s = 0.f;
        #pragma unroll
        for (int cy = 0; cy < 2; ++cy) {
            int yy = y0 + cy;
            if (yy < 0 || yy >= BEV_) continue;
            float wyv = cy ? wy1 : wy0;
            #pragma unroll
            for (int cx = 0; cx < 2; ++cx) {
                int xx = x0 + cx;
                if (xx < 0 || xx >= BEV_) continue;
                float wxv = cx ? wx1 : wx0;
                s += wyv * wxv * mb[((size_t)yy * BEV_ + xx) * D_];
            }
        }
        acc += ws[p] * s;
    }
    fused[(size_t)bq * D_ + h * HD_ + d] = f2bf(acc);
}

// ---------------------------------------------------------------------------
extern "C" void kernel_launch(void* const* d_in, const int* in_sizes, int n_in,
                              void* d_out, int out_size, void* d_ws, size_t ws_size,
                              hipStream_t stream) {
    const float* query     = (const float*)d_in[0];
    const float* memory    = (const float*)d_in[1];
    const float* refp      = (const float*)d_in[2];
    const float* query_pos = (const float*)d_in[3];
    const float* in_w  = (const float*)d_in[4];
    const float* in_b  = (const float*)d_in[5];
    const float* out_w = (const float*)d_in[6];
    const float* out_b = (const float*)d_in[7];
    const float* off_w = (const float*)d_in[8];
    const float* off_b = (const float*)d_in[9];
    const float* wt_w  = (const float*)d_in[10];
    const float* wt_b  = (const float*)d_in[11];
    const float* co_w  = (const float*)d_in[12];
    const float* co_b  = (const float*)d_in[13];
    const float* f_w1  = (const float*)d_in[14];
    const float* f_b1  = (const float*)d_in[15];
    const float* f_w2  = (const float*)d_in[16];
    const float* f_b2  = (const float*)d_in[17];
    const float* n1s = (const float*)d_in[18];
    const float* n1b = (const float*)d_in[19];
    const float* n2s = (const float*)d_in[20];
    const float* n2b = (const float*)d_in[21];
    const float* n3s = (const float*)d_in[22];
    const float* n3b = (const float*)d_in[23];
    float* outp = (float*)d_out;

    // workspace layout (bytes)
    char* w = (char*)d_ws;
    unsigned short* wb      = (unsigned short*)w;              // 1,228,800
    float*          bias_ow = (float*)(w + 1228800);           // 384 (pad)
    unsigned short* ln_bf   = (unsigned short*)(w + 1229184);  // 3,686,400
    float*          q1      = (float*)(w + 4915584);           // 7,372,800
    unsigned short* Qb      = (unsigned short*)(w + 23347584); // 3,932,160
    unsigned short* Kb      = (unsigned short*)(w + 27279744); // 3,932,160
    unsigned short* Vt      = (unsigned short*)(w + 31211904); // 3,932,160 -> end 35,144,064
    // overlays on region formerly used by qkv_bf:
    float*          samp    = (float*)(w + 15053184);          // 2,764,800
    unsigned short* fuse_bf = (unsigned short*)(w + 17817984); // 3,686,400
    unsigned short* h1_bf   = (unsigned short*)(w + 12288384); // 7,372,800
    unsigned short* attn_bf = ln_bf;                           // reuse

    const unsigned short* wb_in  = wb;
    const unsigned short* wb_out = wb + 196608;
    const unsigned short* wb_ow  = wb + 262144;
    const unsigned short* wb_co  = wb + 286720;
    const unsigned short* wb_f1  = wb + 352256;
    const unsigned short* wb_f2  = wb + 483328;

    dim3 blk(256);
    const int M = M_;

    // 0. prologue: weights->bf16, flash pad zero, LN1
    prologue<<<dim3(5161), blk, 0, stream>>>(
        in_w, out_w, off_w, wt_w, co_w, f_w1, f_w2, off_b, wt_b, wb, bias_ow,
        Qb, Kb, Vt, query, query_pos, n1s, n1b, ln_bf);
    // 1. QKV GEMM with fused repack -> Qb/Kb/Vt
    gemm_mfma<0,0,1><<<dim3(6, 57), blk, 0, stream>>>(ln_bf, wb_in, in_b, nullptr,
                                                      nullptr, nullptr, Qb, Kb, Vt,
                                                      M, 768, 256);
    // 2. flash attention -> bf16
    flash_attn<<<dim3(15, 64), blk, 0, stream>>>(Qb, Kb, Vt, attn_bf);
    // 3. out-proj + residual(query) -> q1 fp32
    gemm_mfma<0,0,0><<<dim3(2, 57), blk, 0, stream>>>(attn_bf, wb_out, out_b, query,
                                                      q1, nullptr, nullptr, nullptr, nullptr,
                                                      M, 256, 256);
    // 4. LN2(q1 + pos) -> bf16
    ln_kernel<<<dim3(M / 4), blk, 0, stream>>>(q1, query_pos, n2s, n2b, ln_bf, M);
    // 5. merged off|wt projection + fused prep -> sx/sy/sw
    gemm_offwt_prep<<<dim3(1, 57), blk, 0, stream>>>(
        ln_bf, wb_ow, bias_ow, refp,
        (float4*)samp, (float4*)samp + 57600, (float4*)samp + 115200);
    // 6. bilinear sample + fuse -> bf16
    sample_kernel<<<dim3(B_ * NQ_ * H_ * HD_ / 256), blk, 0, stream>>>(
        memory, (const float4*)samp, (const float4*)samp + 57600,
        (const float4*)samp + 115200, fuse_bf);
    // 7. co-proj + residual(q1) -> d_out fp32
    gemm_mfma<0,0,0><<<dim3(2, 57), blk, 0, stream>>>(fuse_bf, wb_co, co_b, q1,
                                                      outp, nullptr, nullptr, nullptr, nullptr,
                                                      M, 256, 256);
    // 8. LN3(d_out) -> bf16
    ln_kernel<<<dim3(M / 4), blk, 0, stream>>>(outp, nullptr, n3s, n3b, ln_bf, M);
    // 9. FFN1 + ReLU -> bf16 h1
    gemm_mfma<1,1,0><<<dim3(4, 57), blk, 0, stream>>>(ln_bf, wb_f1, f_b1, nullptr,
                                                      nullptr, h1_bf, nullptr, nullptr, nullptr,
                                                      M, 512, 256);
    // 10. FFN2 + residual(d_out) -> d_out
    gemm_mfma<0,0,0><<<dim3(2, 57), blk, 0, stream>>>(h1_bf, wb_f2, f_b2, outp,
                                                      outp, nullptr, nullptr, nullptr, nullptr,
                                                      M, 256, 512);
}

// Round 3
// 659.278 us; speedup vs baseline: 1.0323x; 1.0067x over previous
//
#include <hip/hip_runtime.h>
#include <math.h>

#define B_   8
#define NQ_  900
#define D_   256
#define H_   8
#define P_   4
#define BEV_ 200
#define FFN_ 512
#define HD_  32
#define M_   (B_*NQ_)
#define NKPAD 960

typedef __attribute__((ext_vector_type(8))) short short8;
typedef __attribute__((ext_vector_type(4))) float floatx4;

__device__ inline unsigned short f2bf(float f) {
    union { float f; unsigned u; } v; v.f = f;
    unsigned r = v.u + 0x7fffu + ((v.u >> 16) & 1u);
    return (unsigned short)(r >> 16);
}
__device__ inline float bf2f(unsigned short h) {
    union { unsigned u; float f; } v; v.u = ((unsigned)h) << 16;
    return v.f;
}

// ---------------------------------------------------------------------------
// Prologue: weights fp32->bf16 (blocks [0,2401)), Qb/Kb pad zero [2401,2881),
// Vt pad zero [2881,3361), LN1(query+pos) [3361,5161).
// ---------------------------------------------------------------------------
__global__ __launch_bounds__(256)
void prologue(const float* __restrict__ in_w, const float* __restrict__ out_w,
              const float* __restrict__ off_w, const float* __restrict__ wt_w,
              const float* __restrict__ co_w, const float* __restrict__ f_w1,
              const float* __restrict__ f_w2, const float* __restrict__ off_b,
              const float* __restrict__ wt_b,
              unsigned short* __restrict__ wb, float* __restrict__ bias_ow,
              unsigned short* __restrict__ Qb, unsigned short* __restrict__ Kb,
              unsigned short* __restrict__ Vt,
              const float* __restrict__ query, const float* __restrict__ query_pos,
              const float* __restrict__ n1s, const float* __restrict__ n1b,
              unsigned short* __restrict__ ln_out)
{
    const int bx = blockIdx.x;
    const int t  = threadIdx.x;
    if (bx < 2401) {
        int i = bx * 256 + t;
        if (i < 196608)      { wb[i] = f2bf(in_w[i]); }
        else if (i < 262144) { wb[i] = f2bf(out_w[i - 196608]); }
        else if (i < 278528) { wb[i] = f2bf(off_w[i - 262144]); }
        else if (i < 286720) { wb[i] = f2bf(wt_w[i - 278528]); }
        else if (i < 352256) { wb[i] = f2bf(co_w[i - 286720]); }
        else if (i < 483328) { wb[i] = f2bf(f_w1[i - 352256]); }
        else if (i < 614400) { wb[i] = f2bf(f_w2[i - 483328]); }
        else if (i < 614464) { bias_ow[i - 614400] = off_b[i - 614400]; }
        else if (i < 614496) { bias_ow[i - 614400] = wt_b[i - 614464]; }
    } else if (bx < 2881) {
        int j  = (bx - 2401) * 256 + t;
        int bh = j / 1920;
        int rem = j - bh * 1920;
        int q  = 900 + (rem >> 5);
        int ch = rem & 31;
        size_t idx = ((size_t)bh * NKPAD + q) * 32 + ch;
        Qb[idx] = 0;
        Kb[idx] = 0;
    } else if (bx < 3361) {
        int j  = (bx - 2881) * 256 + t;
        int bh = j / 1920;
        int rem = j - bh * 1920;
        int ch = rem / 60;
        int k  = rem - ch * 60;
        Vt[((size_t)bh * 32 + ch) * NKPAD + 900 + k] = 0;
    } else {
        int w    = t >> 6;
        int lane = t & 63;
        int row  = (bx - 3361) * 4 + w;
        size_t base = (size_t)row * D_ + lane * 4;
        float4 v = *(const float4*)(query + base);
        float4 p = *(const float4*)(query_pos + base);
        v.x += p.x; v.y += p.y; v.z += p.z; v.w += p.w;
        float s = v.x + v.y + v.z + v.w;
        float q = v.x*v.x + v.y*v.y + v.z*v.z + v.w*v.w;
        #pragma unroll
        for (int o = 1; o < 64; o <<= 1) {
            s += __shfl_xor(s, o, 64);
            q += __shfl_xor(q, o, 64);
        }
        float m   = s * (1.0f / D_);
        float var = q * (1.0f / D_) - m * m;
        float inv = rsqrtf(var + 1e-5f);
        float4 g = *(const float4*)(n1s + lane * 4);
        float4 b = *(const float4*)(n1b + lane * 4);
        ushort4 o4;
        o4.x = f2bf((v.x - m) * inv * g.x + b.x);
        o4.y = f2bf((v.y - m) * inv * g.y + b.y);
        o4.z = f2bf((v.z - m) * inv * g.z + b.z);
        o4.w = f2bf((v.w - m) * inv * g.w + b.w);
        *(ushort4*)(ln_out + base) = o4;
    }
}

// ---------------------------------------------------------------------------
// LayerNorm over last dim (256); optional pos add; bf16 out.
// ---------------------------------------------------------------------------
__global__ __launch_bounds__(256)
void ln_kernel(const float* __restrict__ x, const float* __restrict__ pos,
               const float* __restrict__ gamma, const float* __restrict__ beta,
               unsigned short* __restrict__ out, int rows)
{
    int w    = threadIdx.x >> 6;
    int lane = threadIdx.x & 63;
    int row  = blockIdx.x * 4 + w;
    if (row >= rows) return;
    size_t base = (size_t)row * D_ + lane * 4;
    float4 v = *(const float4*)(x + base);
    if (pos) {
        float4 p = *(const float4*)(pos + base);
        v.x += p.x; v.y += p.y; v.z += p.z; v.w += p.w;
    }
    float s = v.x + v.y + v.z + v.w;
    float q = v.x*v.x + v.y*v.y + v.z*v.z + v.w*v.w;
    #pragma unroll
    for (int o = 1; o < 64; o <<= 1) {
        s += __shfl_xor(s, o, 64);
        q += __shfl_xor(q, o, 64);
    }
    float m   = s * (1.0f / D_);
    float var = q * (1.0f / D_) - m * m;
    float inv = rsqrtf(var + 1e-5f);
    float4 g = *(const float4*)(gamma + lane * 4);
    float4 b = *(const float4*)(beta  + lane * 4);
    ushort4 o4;
    o4.x = f2bf((v.x - m) * inv * g.x + b.x);
    o4.y = f2bf((v.y - m) * inv * g.y + b.y);
    o4.z = f2bf((v.z - m) * inv * g.z + b.z);
    o4.w = f2bf((v.w - m) * inv * g.w + b.w);
    *(ushort4*)(out + base) = o4;
}

// ---------------------------------------------------------------------------
// bf16 MFMA GEMM with k-loop software prefetch: next tile's global loads are
// issued after the LDS-ready barrier so they drain during MFMA.
// QKVOUT=1 routes output directly into flash layouts.
// ---------------------------------------------------------------------------
template<int RELU, int OUTBF, int QKVOUT>
__global__ __launch_bounds__(256)
void gemm_mfma(const unsigned short* __restrict__ A, const unsigned short* __restrict__ W,
               const float* __restrict__ bias, const float* __restrict__ res,
               float* __restrict__ outf, unsigned short* __restrict__ outb,
               unsigned short* __restrict__ Qb, unsigned short* __restrict__ Kb,
               unsigned short* __restrict__ Vt,
               int M, int N, int K)
{
    __shared__ unsigned short As[128 * 32];
    __shared__ unsigned short Bs[128 * 32];
    const int t    = threadIdx.x;
    const int m0   = blockIdx.y * 128;
    const int n0   = blockIdx.x * 128;
    const int lane = t & 63;
    const int w    = t >> 6;
    const int wm   = (w >> 1) * 64;
    const int wn   = (w & 1) * 64;
    const int lr   = lane & 15;
    const int kq   = lane >> 4;

    floatx4 acc[4][4];
    #pragma unroll
    for (int i = 0; i < 4; ++i)
        #pragma unroll
        for (int j = 0; j < 4; ++j) acc[i][j] = (floatx4){0.f, 0.f, 0.f, 0.f};

    const int sr = t >> 1;
    const int sc = (t & 1) * 2;
    const int gm = m0 + sr;
    const int gn = n0 + sr;
    const bool am = gm < M;
    const bool bn = gn < N;

    uint4 a0 = {0,0,0,0}, a1 = {0,0,0,0}, b0 = {0,0,0,0}, b1 = {0,0,0,0};
    if (am) {
        const uint4* src = (const uint4*)(A + (size_t)gm * K + sc * 8);
        a0 = src[0]; a1 = src[1];
    }
    if (bn) {
        const uint4* src = (const uint4*)(W + (size_t)gn * K + sc * 8);
        b0 = src[0]; b1 = src[1];
    }

    for (int k0 = 0; k0 < K; k0 += 32) {
        *(uint4*)&As[sr * 32 + ((sc    ) ^ (sr & 3)) * 8] = a0;
        *(uint4*)&As[sr * 32 + ((sc + 1) ^ (sr & 3)) * 8] = a1;
        *(uint4*)&Bs[sr * 32 + ((sc    ) ^ (sr & 3)) * 8] = b0;
        *(uint4*)&Bs[sr * 32 + ((sc + 1) ^ (sr & 3)) * 8] = b1;
        __syncthreads();

        // prefetch next k-tile: loads in flight during ds_read + MFMA
        if (k0 + 32 < K) {
            a0 = (uint4){0,0,0,0}; a1 = a0; b0 = a0; b1 = a0;
            if (am) {
                const uint4* src = (const uint4*)(A + (size_t)gm * K + (k0 + 32) + sc * 8);
                a0 = src[0]; a1 = src[1];
            }
            if (bn) {
                const uint4* src = (const uint4*)(W + (size_t)gn * K + (k0 + 32) + sc * 8);
                b0 = src[0]; b1 = src[1];
            }
        }

        short8 af[4], bfr[4];
        #pragma unroll
        for (int i = 0; i < 4; ++i) {
            int ra = wm + i * 16 + lr;
            af[i] = *(const short8*)&As[ra * 32 + (kq ^ (ra & 3)) * 8];
            int rb = wn + i * 16 + lr;
            bfr[i] = *(const short8*)&Bs[rb * 32 + (kq ^ (rb & 3)) * 8];
        }
        #pragma unroll
        for (int mi = 0; mi < 4; ++mi)
            #pragma unroll
            for (int ni = 0; ni < 4; ++ni)
                acc[mi][ni] = __builtin_amdgcn_mfma_f32_16x16x32_bf16(
                    af[mi], bfr[ni], acc[mi][ni], 0, 0, 0);
        __syncthreads();
    }

    const int rbase = kq * 4;
    #pragma unroll
    for (int ni = 0; ni < 4; ++ni) {
        int n = n0 + wn + ni * 16 + lr;
        if (n >= N) continue;
        float bv = bias[n];
        if (QKVOUT) {
            const int type = n >> 8;
            const int hh   = (n >> 5) & 7;
            const int ch   = n & 31;
            #pragma unroll
            for (int mi = 0; mi < 4; ++mi) {
                floatx4 c = acc[mi][ni];
                #pragma unroll
                for (int r = 0; r < 4; ++r) {
                    int m = m0 + wm + mi * 16 + rbase + r;
                    if (m < M) {
                        float vl = c[r] + bv;
                        int bb = m / 900;
                        int qq = m - bb * 900;
                        size_t bh = (size_t)(bb * 8 + hh);
                        if (type == 0)
                            Qb[(bh * NKPAD + qq) * 32 + ch] = f2bf(vl * 0.17677669529663687f);
                        else if (type == 1)
                            Kb[(bh * NKPAD + qq) * 32 + ch] = f2bf(vl);
                        else
                            Vt[(bh * 32 + ch) * NKPAD + qq] = f2bf(vl);
                    }
                }
            }
        } else {
            #pragma unroll
            for (int mi = 0; mi < 4; ++mi) {
                floatx4 c = acc[mi][ni];
                #pragma unroll
                for (int r = 0; r < 4; ++r) {
                    int m = m0 + wm + mi * 16 + rbase + r;
                    if (m < M) {
                        float vl = c[r] + bv;
                        if (res) vl += res[(size_t)m * N + n];
                        if (RELU) vl = fmaxf(vl, 0.f);
                        if (OUTBF) outb[(size_t)m * N + n] = f2bf(vl);
                        else       outf[(size_t)m * N + n] = vl;
                    }
                }
            }
        }
    }
}

// ---------------------------------------------------------------------------
// off|wt GEMM (M=7200, N=96, K=256, grid (1,57)) with fused prep epilogue.
// Same k-loop prefetch as gemm_mfma.
// ---------------------------------------------------------------------------
__global__ __launch_bounds__(256)
void gemm_offwt_prep(const unsigned short* __restrict__ A, const unsigned short* __restrict__ W,
                     const float* __restrict__ bias, const float* __restrict__ refp,
                     float4* __restrict__ sx, float4* __restrict__ sy, float4* __restrict__ sw)
{
    __shared__ unsigned short As[128 * 32];
    __shared__ unsigned short Bs[128 * 32];
    __shared__ float T[128][100];
    const int t    = threadIdx.x;
    const int m0   = blockIdx.y * 128;
    const int lane = t & 63;
    const int w    = t >> 6;
    const int wm   = (w >> 1) * 64;
    const int wn   = (w & 1) * 64;
    const int lr   = lane & 15;
    const int kq   = lane >> 4;
    const int M = M_, N = 96, K = 256;

    floatx4 acc[4][4];
    #pragma unroll
    for (int i = 0; i < 4; ++i)
        #pragma unroll
        for (int j = 0; j < 4; ++j) acc[i][j] = (floatx4){0.f, 0.f, 0.f, 0.f};

    const int sr = t >> 1;
    const int sc = (t & 1) * 2;
    const int gm = m0 + sr;
    const int gn = sr;
    const bool am = gm < M;
    const bool bn = gn < N;

    uint4 a0 = {0,0,0,0}, a1 = {0,0,0,0}, b0 = {0,0,0,0}, b1 = {0,0,0,0};
    if (am) {
        const uint4* src = (const uint4*)(A + (size_t)gm * K + sc * 8);
        a0 = src[0]; a1 = src[1];
    }
    if (bn) {
        const uint4* src = (const uint4*)(W + (size_t)gn * K + sc * 8);
        b0 = src[0]; b1 = src[1];
    }

    for (int k0 = 0; k0 < K; k0 += 32) {
        *(uint4*)&As[sr * 32 + ((sc    ) ^ (sr & 3)) * 8] = a0;
        *(uint4*)&As[sr * 32 + ((sc + 1) ^ (sr & 3)) * 8] = a1;
        *(uint4*)&Bs[sr * 32 + ((sc    ) ^ (sr & 3)) * 8] = b0;
        *(uint4*)&Bs[sr * 32 + ((sc + 1) ^ (sr & 3)) * 8] = b1;
        __syncthreads();

        if (k0 + 32 < K) {
            a0 = (uint4){0,0,0,0}; a1 = a0; b0 = a0; b1 = a0;
            if (am) {
                const uint4* src = (const uint4*)(A + (size_t)gm * K + (k0 + 32) + sc * 8);
                a0 = src[0]; a1 = src[1];
            }
            if (bn) {
                const uint4* src = (const uint4*)(W + (size_t)gn * K + (k0 + 32) + sc * 8);
                b0 = src[0]; b1 = src[1];
            }
        }

        short8 af[4], bfr[4];
        #pragma unroll
        for (int i = 0; i < 4; ++i) {
            int ra = wm + i * 16 + lr;
            af[i] = *(const short8*)&As[ra * 32 + (kq ^ (ra & 3)) * 8];
            int rb = wn + i * 16 + lr;
            bfr[i] = *(const short8*)&Bs[rb * 32 + (kq ^ (rb & 3)) * 8];
        }
        #pragma unroll
        for (int mi = 0; mi < 4; ++mi)
            #pragma unroll
            for (int ni = 0; ni < 4; ++ni)
                acc[mi][ni] = __builtin_amdgcn_mfma_f32_16x16x32_bf16(
                    af[mi], bfr[ni], acc[mi][ni], 0, 0, 0);
        __syncthreads();
    }

    const int rbase = kq * 4;
    #pragma unroll
    for (int ni = 0; ni < 4; ++ni) {
        int n = wn + ni * 16 + lr;
        if (n >= N) continue;
        float bv = bias[n];
        #pragma unroll
        for (int mi = 0; mi < 4; ++mi) {
            floatx4 c = acc[mi][ni];
            #pragma unroll
            for (int r = 0; r < 4; ++r)
                T[wm + mi * 16 + rbase + r][n] = c[r] + bv;
        }
    }
    __syncthreads();

    #pragma unroll
    for (int it = 0; it < 4; ++it) {
        int item = t + it * 256;
        int row  = item >> 3;
        int h    = item & 7;
        int gq   = m0 + row;
        if (gq >= M) continue;
        float rx = refp[gq * 2 + 0];
        float ry = refp[gq * 2 + 1];
        const float* orow = &T[row][h * 8];
        const float* wrow = &T[row][64 + h * 4];
        float gx[4], gy[4], wv[4];
        #pragma unroll
        for (int p = 0; p < 4; ++p) {
            float ox = tanhf(orow[p * 2 + 0]) * 0.2f;
            float oy = tanhf(orow[p * 2 + 1]) * 0.2f;
            gx[p] = (rx + ox) * (float)BEV_ - 0.5f;
            gy[p] = (ry + oy) * (float)BEV_ - 0.5f;
            wv[p] = wrow[p];
        }
        float mx = fmaxf(fmaxf(wv[0], wv[1]), fmaxf(wv[2], wv[3]));
        float e0 = expf(wv[0]-mx), e1 = expf(wv[1]-mx), e2 = expf(wv[2]-mx), e3 = expf(wv[3]-mx);
        float inv = 1.f / (e0 + e1 + e2 + e3);
        int idx = gq * 8 + h;
        sx[idx] = make_float4(gx[0], gx[1], gx[2], gx[3]);
        sy[idx] = make_float4(gy[0], gy[1], gy[2], gy[3]);
        sw[idx] = make_float4(e0*inv, e1*inv, e2*inv, e3*inv);
    }
}

// ---------------------------------------------------------------------------
// Flash self-attention. Grid (15, 64). 4 waves/block; wave owns 16 q-rows.
// K-fragment prefetch + early V loads + double-buffered P_lds (no trailing
// LDS drain).
// ---------------------------------------------------------------------------
__global__ __launch_bounds__(256)
void flash_attn(const unsigned short* __restrict__ Qb, const unsigned short* __restrict__ Kb,
                const unsigned short* __restrict__ Vt, unsigned short* __restrict__ out)
{
    __shared__ unsigned short P_lds[4][2][16][72];
    const int bh   = blockIdx.y;
    const int b    = bh >> 3, h = bh & 7;
    const int q0   = blockIdx.x * 64;
    const int w    = threadIdx.x >> 6;
    const int lane = threadIdx.x & 63;
    const int lr   = lane & 15;
    const int quad = lane >> 4;

    const short8 qfrag = *(const short8*)(Qb + ((size_t)bh * NKPAD + q0 + w * 16 + lr) * 32 + quad * 8);

    floatx4 O0 = (floatx4){0.f,0.f,0.f,0.f};
    floatx4 O1 = (floatx4){0.f,0.f,0.f,0.f};
    float m_i[4] = {-INFINITY, -INFINITY, -INFINITY, -INFINITY};
    float l_i[4] = {0.f, 0.f, 0.f, 0.f};

    const unsigned short* kbase_p = Kb + (size_t)bh * NKPAD * 32;
    const unsigned short* vbase_p = Vt + (size_t)bh * 32 * NKPAD;

    short8 kf[4], kfn[4];
    #pragma unroll
    for (int ni = 0; ni < 4; ++ni)
        kf[ni] = *(const short8*)(kbase_p + (size_t)(ni * 16 + lr) * 32 + quad * 8);

    for (int kt = 0; kt < 15; ++kt) {
        const int kb = kt * 64;
        // --- QK^T ---
        floatx4 S[4];
        #pragma unroll
        for (int ni = 0; ni < 4; ++ni)
            S[ni] = __builtin_amdgcn_mfma_f32_16x16x32_bf16(
                qfrag, kf[ni], (floatx4){0.f,0.f,0.f,0.f}, 0, 0, 0);
        // --- prefetch next K-tile fragments (in flight during softmax+PV) ---
        if (kt < 14) {
            #pragma unroll
            for (int ni = 0; ni < 4; ++ni)
                kfn[ni] = *(const short8*)(kbase_p + (size_t)(kb + 64 + ni * 16 + lr) * 32 + quad * 8);
        }
        // --- issue V loads early (independent of softmax/LDS) ---
        short8 vf0 = *(const short8*)(vbase_p + (size_t)(lr) * NKPAD + kb + quad * 8);
        short8 vf1 = *(const short8*)(vbase_p + (size_t)(lr) * NKPAD + kb + 32 + quad * 8);
        short8 vf2 = *(const short8*)(vbase_p + (size_t)(16 + lr) * NKPAD + kb + quad * 8);
        short8 vf3 = *(const short8*)(vbase_p + (size_t)(16 + lr) * NKPAD + kb + 32 + quad * 8);
        // --- mask tail keys ---
        if (kt == 14) {
            #pragma unroll
            for (int ni = 0; ni < 4; ++ni) {
                int key = kb + ni * 16 + lr;
                if (key >= NQ_) S[ni] = (floatx4){-1e30f, -1e30f, -1e30f, -1e30f};
            }
        }
        // --- online softmax ---
        float rowmax[4];
        #pragma unroll
        for (int r = 0; r < 4; ++r)
            rowmax[r] = fmaxf(fmaxf(S[0][r], S[1][r]), fmaxf(S[2][r], S[3][r]));
        #pragma unroll
        for (int off = 1; off < 16; off <<= 1)
            #pragma unroll
            for (int r = 0; r < 4; ++r)
                rowmax[r] = fmaxf(rowmax[r], __shfl_xor(rowmax[r], off, 64));
        float alpha[4], rs[4];
        #pragma unroll
        for (int r = 0; r < 4; ++r) {
            float mnew = fmaxf(m_i[r], rowmax[r]);
            alpha[r] = __expf(m_i[r] - mnew);
            m_i[r] = mnew;
            rs[r] = 0.f;
        }
        const int buf = kt & 1;
        #pragma unroll
        for (int ni = 0; ni < 4; ++ni) {
            #pragma unroll
            for (int r = 0; r < 4; ++r) {
                float p = __expf(S[ni][r] - m_i[r]);
                rs[r] += p;
                P_lds[w][buf][quad * 4 + r][ni * 16 + lr] = f2bf(p);
            }
        }
        #pragma unroll
        for (int off = 1; off < 16; off <<= 1)
            #pragma unroll
            for (int r = 0; r < 4; ++r)
                rs[r] += __shfl_xor(rs[r], off, 64);
        #pragma unroll
        for (int r = 0; r < 4; ++r) {
            l_i[r] = alpha[r] * l_i[r] + rs[r];
            O0[r] *= alpha[r];
            O1[r] *= alpha[r];
        }
        // wave-internal LDS RAW: drain ds_writes before ds_reads
        asm volatile("s_waitcnt lgkmcnt(0)" ::: "memory");
        short8 pf0 = *(const short8*)&P_lds[w][buf][lr][quad * 8];
        short8 pf1 = *(const short8*)&P_lds[w][buf][lr][32 + quad * 8];
        O0 = __builtin_amdgcn_mfma_f32_16x16x32_bf16(pf0, vf0, O0, 0, 0, 0);
        O0 = __builtin_amdgcn_mfma_f32_16x16x32_bf16(pf1, vf1, O0, 0, 0, 0);
        O1 = __builtin_amdgcn_mfma_f32_16x16x32_bf16(pf0, vf2, O1, 0, 0, 0);
        O1 = __builtin_amdgcn_mfma_f32_16x16x32_bf16(pf1, vf3, O1, 0, 0, 0);
        // no trailing drain: next iteration writes the other P buffer
        if (kt < 14) {
            #pragma unroll
            for (int ni = 0; ni < 4; ++ni) kf[ni] = kfn[ni];
        }
    }
    #pragma unroll
    for (int r = 0; r < 4; ++r) {
        int q = q0 + w * 16 + quad * 4 + r;
        if (q < NQ_) {
            float inv = 1.f / l_i[r];
            size_t base = ((size_t)(b * NQ_ + q)) * D_ + h * 32;
            out[base + lr]      = f2bf(O0[r] * inv);
            out[base + 16 + lr] = f2bf(O1[r] * inv);
        }
    }
}

// ---------------------------------------------------------------------------
// Bilinear sampler; bf16 out.
// ---------------------------------------------------------------------------
__global__ __launch_bounds__(256)
void sample_kernel(const float* __restrict__ mem,
                   const float4* __restrict__ sx, const float4* __restrict__ sy,
                   const float4* __restrict__ sw, unsigned short* __restrict__ fused)
{
    int tid = blockIdx.x * 256 + threadIdx.x;
    if (tid >= B_ * NQ_ * H_ * HD_) return;
    int d   = tid & 31;
    int bqh = tid >> 5;
    int h   = bqh & 7;
    int bq  = bqh >> 3;
    int b   = bq / NQ_;
    const float* mb = mem + (size_t)b * (BEV_ * BEV_) * D_ + h * HD_ + d;
    float4 X = sx[bqh], Y = sy[bqh], W = sw[bqh];
    float xs[4] = {X.x, X.y, X.z, X.w};
    float ys[4] = {Y.x, Y.y, Y.z, Y.w};
    float ws[4] = {W.x, W.y, W.z, W.w};
    float acc = 0.f;
    #pragma unroll
    for (int p = 0; p < 4; ++p) {
        float gx = xs[p], gy = ys[p];
        float x0f = floorf(gx), y0f = floorf(gy);
        int x0 = (int)x0f, y0 = (int)y0f;
        float wx1 = gx - x0f, wy1 = gy - y0f;
        float wx0 = 1.f - wx1, wy0 = 1.f - wy1;
        float s = 0.f;
        #pragma unroll
        for (int cy = 0; cy < 2; ++cy) {
            int yy = y0 + cy;
            if (yy < 0 || yy >= BEV_) continue;
            float wyv = cy ? wy1 : wy0;
            #pragma unroll
            for (int cx = 0; cx < 2; ++cx) {
                int xx = x0 + cx;
                if (xx < 0 || xx >= BEV_) continue;
                float wxv = cx ? wx1 : wx0;
                s += wyv * wxv * mb[((size_t)yy * BEV_ + xx) * D_];
            }
        }
        acc += ws[p] * s;
    }
    fused[(size_t)bq * D_ + h * HD_ + d] = f2bf(acc);
}

// ---------------------------------------------------------------------------
extern "C" void kernel_launch(void* const* d_in, const int* in_sizes, int n_in,
                              void* d_out, int out_size, void* d_ws, size_t ws_size,
                              hipStream_t stream) {
    const float* query     = (const float*)d_in[0];
    const float* memory    = (const float*)d_in[1];
    const float* refp      = (const float*)d_in[2];
    const float* query_pos = (const float*)d_in[3];
    const float* in_w  = (const float*)d_in[4];
    const float* in_b  = (const float*)d_in[5];
    const float* out_w = (const float*)d_in[6];
    const float* out_b = (const float*)d_in[7];
    const float* off_w = (const float*)d_in[8];
    const float* off_b = (const float*)d_in[9];
    const float* wt_w  = (const float*)d_in[10];
    const float* wt_b  = (const float*)d_in[11];
    const float* co_w  = (const float*)d_in[12];
    const float* co_b  = (const float*)d_in[13];
    const float* f_w1  = (const float*)d_in[14];
    const float* f_b1  = (const float*)d_in[15];
    const float* f_w2  = (const float*)d_in[16];
    const float* f_b2  = (const float*)d_in[17];
    const float* n1s = (const float*)d_in[18];
    const float* n1b = (const float*)d_in[19];
    const float* n2s = (const float*)d_in[20];
    const float* n2b = (const float*)d_in[21];
    const float* n3s = (const float*)d_in[22];
    const float* n3b = (const float*)d_in[23];
    float* outp = (float*)d_out;

    // workspace layout (bytes)
    char* w = (char*)d_ws;
    unsigned short* wb      = (unsigned short*)w;              // 1,228,800
    float*          bias_ow = (float*)(w + 1228800);           // 384 (pad)
    unsigned short* ln_bf   = (unsigned short*)(w + 1229184);  // 3,686,400
    float*          q1      = (float*)(w + 4915584);           // 7,372,800
    unsigned short* Qb      = (unsigned short*)(w + 23347584); // 3,932,160
    unsigned short* Kb      = (unsigned short*)(w + 27279744); // 3,932,160
    unsigned short* Vt      = (unsigned short*)(w + 31211904); // 3,932,160 -> end 35,144,064
    // overlays:
    float*          samp    = (float*)(w + 15053184);          // 2,764,800
    unsigned short* fuse_bf = (unsigned short*)(w + 17817984); // 3,686,400
    unsigned short* h1_bf   = (unsigned short*)(w + 12288384); // 7,372,800
    unsigned short* attn_bf = ln_bf;                           // reuse

    const unsigned short* wb_in  = wb;
    const unsigned short* wb_out = wb + 196608;
    const unsigned short* wb_ow  = wb + 262144;
    const unsigned short* wb_co  = wb + 286720;
    const unsigned short* wb_f1  = wb + 352256;
    const unsigned short* wb_f2  = wb + 483328;

    dim3 blk(256);
    const int M = M_;

    // 0. prologue: weights->bf16, flash pad zero, LN1
    prologue<<<dim3(5161), blk, 0, stream>>>(
        in_w, out_w, off_w, wt_w, co_w, f_w1, f_w2, off_b, wt_b, wb, bias_ow,
        Qb, Kb, Vt, query, query_pos, n1s, n1b, ln_bf);
    // 1. QKV GEMM with fused repack -> Qb/Kb/Vt
    gemm_mfma<0,0,1><<<dim3(6, 57), blk, 0, stream>>>(ln_bf, wb_in, in_b, nullptr,
                                                      nullptr, nullptr, Qb, Kb, Vt,
                                                      M, 768, 256);
    // 2. flash attention -> bf16
    flash_attn<<<dim3(15, 64), blk, 0, stream>>>(Qb, Kb, Vt, attn_bf);
    // 3. out-proj + residual(query) -> q1 fp32
    gemm_mfma<0,0,0><<<dim3(2, 57), blk, 0, stream>>>(attn_bf, wb_out, out_b, query,
                                                      q1, nullptr, nullptr, nullptr, nullptr,
                                                      M, 256, 256);
    // 4. LN2(q1 + pos) -> bf16
    ln_kernel<<<dim3(M / 4), blk, 0, stream>>>(q1, query_pos, n2s, n2b, ln_bf, M);
    // 5. merged off|wt projection + fused prep -> sx/sy/sw
    gemm_offwt_prep<<<dim3(1, 57), blk, 0, stream>>>(
        ln_bf, wb_ow, bias_ow, refp,
        (float4*)samp, (float4*)samp + 57600, (float4*)samp + 115200);
    // 6. bilinear sample + fuse -> bf16
    sample_kernel<<<dim3(B_ * NQ_ * H_ * HD_ / 256), blk, 0, stream>>>(
        memory, (const float4*)samp, (const float4*)samp + 57600,
        (const float4*)samp + 115200, fuse_bf);
    // 7. co-proj + residual(q1) -> d_out fp32
    gemm_mfma<0,0,0><<<dim3(2, 57), blk, 0, stream>>>(fuse_bf, wb_co, co_b, q1,
                                                      outp, nullptr, nullptr, nullptr, nullptr,
                                                      M, 256, 256);
    // 8. LN3(d_out) -> bf16
    ln_kernel<<<dim3(M / 4), blk, 0, stream>>>(outp, nullptr, n3s, n3b, ln_bf, M);
    // 9. FFN1 + ReLU -> bf16 h1
    gemm_mfma<1,1,0><<<dim3(4, 57), blk, 0, stream>>>(ln_bf, wb_f1, f_b1, nullptr,
                                                      nullptr, h1_bf, nullptr, nullptr, nullptr,
                                                      M, 512, 256);
    // 10. FFN2 + residual(d_out) -> d_out
    gemm_mfma<0,0,0><<<dim3(2, 57), blk, 0, stream>>>(h1_bf, wb_f2, f_b2, outp,
                                                      outp, nullptr, nullptr, nullptr, nullptr,
                                                      M, 256, 512);
}

// Round 4
// 657.270 us; speedup vs baseline: 1.0354x; 1.0031x over previous
//
#include <hip/hip_runtime.h>
#include <math.h>

#define B_   8
#define NQ_  900
#define D_   256
#define H_   8
#define P_   4
#define BEV_ 200
#define FFN_ 512
#define HD_  32
#define M_   (B_*NQ_)
#define NKPAD 960

typedef __attribute__((ext_vector_type(8))) short short8;
typedef __attribute__((ext_vector_type(4))) float floatx4;

__device__ inline unsigned short f2bf(float f) {
    union { float f; unsigned u; } v; v.f = f;
    unsigned r = v.u + 0x7fffu + ((v.u >> 16) & 1u);
    return (unsigned short)(r >> 16);
}
__device__ inline float bf2f(unsigned short h) {
    union { unsigned u; float f; } v; v.u = ((unsigned)h) << 16;
    return v.f;
}

// ---------------------------------------------------------------------------
// Prologue: weights fp32->bf16 (blocks [0,2401)), Qb/Kb pad zero [2401,2881),
// Vt pad zero [2881,3361), LN1(query+pos) [3361,5161).
// ---------------------------------------------------------------------------
__global__ __launch_bounds__(256)
void prologue(const float* __restrict__ in_w, const float* __restrict__ out_w,
              const float* __restrict__ off_w, const float* __restrict__ wt_w,
              const float* __restrict__ co_w, const float* __restrict__ f_w1,
              const float* __restrict__ f_w2, const float* __restrict__ off_b,
              const float* __restrict__ wt_b,
              unsigned short* __restrict__ wb, float* __restrict__ bias_ow,
              unsigned short* __restrict__ Qb, unsigned short* __restrict__ Kb,
              unsigned short* __restrict__ Vt,
              const float* __restrict__ query, const float* __restrict__ query_pos,
              const float* __restrict__ n1s, const float* __restrict__ n1b,
              unsigned short* __restrict__ ln_out)
{
    const int bx = blockIdx.x;
    const int t  = threadIdx.x;
    if (bx < 2401) {
        int i = bx * 256 + t;
        if (i < 196608)      { wb[i] = f2bf(in_w[i]); }
        else if (i < 262144) { wb[i] = f2bf(out_w[i - 196608]); }
        else if (i < 278528) { wb[i] = f2bf(off_w[i - 262144]); }
        else if (i < 286720) { wb[i] = f2bf(wt_w[i - 278528]); }
        else if (i < 352256) { wb[i] = f2bf(co_w[i - 286720]); }
        else if (i < 483328) { wb[i] = f2bf(f_w1[i - 352256]); }
        else if (i < 614400) { wb[i] = f2bf(f_w2[i - 483328]); }
        else if (i < 614464) { bias_ow[i - 614400] = off_b[i - 614400]; }
        else if (i < 614496) { bias_ow[i - 614400] = wt_b[i - 614464]; }
    } else if (bx < 2881) {
        int j  = (bx - 2401) * 256 + t;
        int bh = j / 1920;
        int rem = j - bh * 1920;
        int q  = 900 + (rem >> 5);
        int ch = rem & 31;
        size_t idx = ((size_t)bh * NKPAD + q) * 32 + ch;
        Qb[idx] = 0;
        Kb[idx] = 0;
    } else if (bx < 3361) {
        int j  = (bx - 2881) * 256 + t;
        int bh = j / 1920;
        int rem = j - bh * 1920;
        int ch = rem / 60;
        int k  = rem - ch * 60;
        Vt[((size_t)bh * 32 + ch) * NKPAD + 900 + k] = 0;
    } else {
        int w    = t >> 6;
        int lane = t & 63;
        int row  = (bx - 3361) * 4 + w;
        size_t base = (size_t)row * D_ + lane * 4;
        float4 v = *(const float4*)(query + base);
        float4 p = *(const float4*)(query_pos + base);
        v.x += p.x; v.y += p.y; v.z += p.z; v.w += p.w;
        float s = v.x + v.y + v.z + v.w;
        float q = v.x*v.x + v.y*v.y + v.z*v.z + v.w*v.w;
        #pragma unroll
        for (int o = 1; o < 64; o <<= 1) {
            s += __shfl_xor(s, o, 64);
            q += __shfl_xor(q, o, 64);
        }
        float m   = s * (1.0f / D_);
        float var = q * (1.0f / D_) - m * m;
        float inv = rsqrtf(var + 1e-5f);
        float4 g = *(const float4*)(n1s + lane * 4);
        float4 b = *(const float4*)(n1b + lane * 4);
        ushort4 o4;
        o4.x = f2bf((v.x - m) * inv * g.x + b.x);
        o4.y = f2bf((v.y - m) * inv * g.y + b.y);
        o4.z = f2bf((v.z - m) * inv * g.z + b.z);
        o4.w = f2bf((v.w - m) * inv * g.w + b.w);
        *(ushort4*)(ln_out + base) = o4;
    }
}

// ---------------------------------------------------------------------------
// bf16 MFMA GEMM with k-loop software prefetch.
// QKVOUT=1 routes output directly into flash layouts.
// ---------------------------------------------------------------------------
template<int RELU, int OUTBF, int QKVOUT>
__global__ __launch_bounds__(256)
void gemm_mfma(const unsigned short* __restrict__ A, const unsigned short* __restrict__ W,
               const float* __restrict__ bias, const float* __restrict__ res,
               float* __restrict__ outf, unsigned short* __restrict__ outb,
               unsigned short* __restrict__ Qb, unsigned short* __restrict__ Kb,
               unsigned short* __restrict__ Vt,
               int M, int N, int K)
{
    __shared__ unsigned short As[128 * 32];
    __shared__ unsigned short Bs[128 * 32];
    const int t    = threadIdx.x;
    const int m0   = blockIdx.y * 128;
    const int n0   = blockIdx.x * 128;
    const int lane = t & 63;
    const int w    = t >> 6;
    const int wm   = (w >> 1) * 64;
    const int wn   = (w & 1) * 64;
    const int lr   = lane & 15;
    const int kq   = lane >> 4;

    floatx4 acc[4][4];
    #pragma unroll
    for (int i = 0; i < 4; ++i)
        #pragma unroll
        for (int j = 0; j < 4; ++j) acc[i][j] = (floatx4){0.f, 0.f, 0.f, 0.f};

    const int sr = t >> 1;
    const int sc = (t & 1) * 2;
    const int gm = m0 + sr;
    const int gn = n0 + sr;
    const bool am = gm < M;
    const bool bn = gn < N;

    uint4 a0 = {0,0,0,0}, a1 = {0,0,0,0}, b0 = {0,0,0,0}, b1 = {0,0,0,0};
    if (am) {
        const uint4* src = (const uint4*)(A + (size_t)gm * K + sc * 8);
        a0 = src[0]; a1 = src[1];
    }
    if (bn) {
        const uint4* src = (const uint4*)(W + (size_t)gn * K + sc * 8);
        b0 = src[0]; b1 = src[1];
    }

    for (int k0 = 0; k0 < K; k0 += 32) {
        *(uint4*)&As[sr * 32 + ((sc    ) ^ (sr & 3)) * 8] = a0;
        *(uint4*)&As[sr * 32 + ((sc + 1) ^ (sr & 3)) * 8] = a1;
        *(uint4*)&Bs[sr * 32 + ((sc    ) ^ (sr & 3)) * 8] = b0;
        *(uint4*)&Bs[sr * 32 + ((sc + 1) ^ (sr & 3)) * 8] = b1;
        __syncthreads();

        if (k0 + 32 < K) {
            a0 = (uint4){0,0,0,0}; a1 = a0; b0 = a0; b1 = a0;
            if (am) {
                const uint4* src = (const uint4*)(A + (size_t)gm * K + (k0 + 32) + sc * 8);
                a0 = src[0]; a1 = src[1];
            }
            if (bn) {
                const uint4* src = (const uint4*)(W + (size_t)gn * K + (k0 + 32) + sc * 8);
                b0 = src[0]; b1 = src[1];
            }
        }

        short8 af[4], bfr[4];
        #pragma unroll
        for (int i = 0; i < 4; ++i) {
            int ra = wm + i * 16 + lr;
            af[i] = *(const short8*)&As[ra * 32 + (kq ^ (ra & 3)) * 8];
            int rb = wn + i * 16 + lr;
            bfr[i] = *(const short8*)&Bs[rb * 32 + (kq ^ (rb & 3)) * 8];
        }
        #pragma unroll
        for (int mi = 0; mi < 4; ++mi)
            #pragma unroll
            for (int ni = 0; ni < 4; ++ni)
                acc[mi][ni] = __builtin_amdgcn_mfma_f32_16x16x32_bf16(
                    af[mi], bfr[ni], acc[mi][ni], 0, 0, 0);
        __syncthreads();
    }

    const int rbase = kq * 4;
    #pragma unroll
    for (int ni = 0; ni < 4; ++ni) {
        int n = n0 + wn + ni * 16 + lr;
        if (n >= N) continue;
        float bv = bias[n];
        if (QKVOUT) {
            const int type = n >> 8;
            const int hh   = (n >> 5) & 7;
            const int ch   = n & 31;
            #pragma unroll
            for (int mi = 0; mi < 4; ++mi) {
                floatx4 c = acc[mi][ni];
                #pragma unroll
                for (int r = 0; r < 4; ++r) {
                    int m = m0 + wm + mi * 16 + rbase + r;
                    if (m < M) {
                        float vl = c[r] + bv;
                        int bb = m / 900;
                        int qq = m - bb * 900;
                        size_t bh = (size_t)(bb * 8 + hh);
                        if (type == 0)
                            Qb[(bh * NKPAD + qq) * 32 + ch] = f2bf(vl * 0.17677669529663687f);
                        else if (type == 1)
                            Kb[(bh * NKPAD + qq) * 32 + ch] = f2bf(vl);
                        else
                            Vt[(bh * 32 + ch) * NKPAD + qq] = f2bf(vl);
                    }
                }
            }
        } else {
            #pragma unroll
            for (int mi = 0; mi < 4; ++mi) {
                floatx4 c = acc[mi][ni];
                #pragma unroll
                for (int r = 0; r < 4; ++r) {
                    int m = m0 + wm + mi * 16 + rbase + r;
                    if (m < M) {
                        float vl = c[r] + bv;
                        if (res) vl += res[(size_t)m * N + n];
                        if (RELU) vl = fmaxf(vl, 0.f);
                        if (OUTBF) outb[(size_t)m * N + n] = f2bf(vl);
                        else       outf[(size_t)m * N + n] = vl;
                    }
                }
            }
        }
    }
}

// ---------------------------------------------------------------------------
// Projection GEMM (N=256, K=256) with fused residual + LayerNorm epilogue.
// 512 threads, BM=128, BN=256. 8 waves; wave w owns rows [w*16, w*16+16)
// across ALL 256 cols -> LN row-reduce is a 16-lane shfl, no cross-wave LDS.
// Writes: outf[m][n] = acc + bias + res   (fp32, pre-LN, for later residual)
//         lnout[m][n] = LN(outf (+pos)) * gamma + beta   (bf16)
// POS=1 adds pos before LN (LN2 case); POS=0 (LN3 case).
// Safe when A aliases lnout: each block reads only its own 128-row slab of A,
// and all A loads complete before the epilogue writes.
// ---------------------------------------------------------------------------
template<int POS>
__global__ __launch_bounds__(512)
void gemm_resln(const unsigned short* __restrict__ A, const unsigned short* __restrict__ W,
                const float* __restrict__ bias, const float* __restrict__ res,
                const float* __restrict__ pos,
                const float* __restrict__ gamma, const float* __restrict__ beta,
                float* __restrict__ outf, unsigned short* __restrict__ lnout)
{
    __shared__ unsigned short As[128 * 32];
    __shared__ unsigned short Bs[256 * 32];
    const int t    = threadIdx.x;
    const int m0   = blockIdx.x * 128;
    const int lane = t & 63;
    const int w    = t >> 6;            // 0..7, wave rows = w*16..+16
    const int lr   = lane & 15;
    const int quad = lane >> 4;
    const int M = M_, K = 256;

    floatx4 acc[16];
    #pragma unroll
    for (int i = 0; i < 16; ++i) acc[i] = (floatx4){0.f, 0.f, 0.f, 0.f};

    // A staging: thread t -> row t>>2 (0..127), quarter t&3 (8 bf16)
    const int ar = t >> 2;
    const int aq = t & 3;
    const int gm = m0 + ar;
    const bool am = gm < M;
    // B staging: thread t -> row t>>1 (0..255), half t&1 (16 bf16 = 2 quarters)
    const int br = t >> 1;
    const int bq2 = (t & 1) * 2;

    uint4 apf = {0,0,0,0}, bpf0 = {0,0,0,0}, bpf1 = {0,0,0,0};
    if (am) apf = *(const uint4*)(A + (size_t)gm * K + aq * 8);
    {
        const uint4* src = (const uint4*)(W + (size_t)br * K + bq2 * 8);
        bpf0 = src[0]; bpf1 = src[1];
    }

    for (int k0 = 0; k0 < K; k0 += 32) {
        *(uint4*)&As[ar * 32 + (aq ^ (ar & 3)) * 8] = apf;
        *(uint4*)&Bs[br * 32 + ((bq2    ) ^ (br & 3)) * 8] = bpf0;
        *(uint4*)&Bs[br * 32 + ((bq2 + 1) ^ (br & 3)) * 8] = bpf1;
        __syncthreads();

        if (k0 + 32 < K) {
            apf = (uint4){0,0,0,0};
            if (am) apf = *(const uint4*)(A + (size_t)gm * K + (k0 + 32) + aq * 8);
            const uint4* src = (const uint4*)(W + (size_t)br * K + (k0 + 32) + bq2 * 8);
            bpf0 = src[0]; bpf1 = src[1];
        }

        const int ra = w * 16 + lr;
        short8 af = *(const short8*)&As[ra * 32 + ((lane >> 4) ^ (ra & 3)) * 8];
        #pragma unroll
        for (int half = 0; half < 2; ++half) {
            short8 bfr[8];
            #pragma unroll
            for (int i = 0; i < 8; ++i) {
                int rb = (half * 8 + i) * 16 + lr;
                bfr[i] = *(const short8*)&Bs[rb * 32 + ((lane >> 4) ^ (rb & 3)) * 8];
            }
            #pragma unroll
            for (int i = 0; i < 8; ++i)
                acc[half * 8 + i] = __builtin_amdgcn_mfma_f32_16x16x32_bf16(
                    af, bfr[i], acc[half * 8 + i], 0, 0, 0);
        }
        __syncthreads();
    }

    // ---- epilogue: bias + residual -> fp32 out; LN(+pos) -> bf16 ----
    float s[4] = {0.f, 0.f, 0.f, 0.f};
    float q[4] = {0.f, 0.f, 0.f, 0.f};
    #pragma unroll
    for (int ni = 0; ni < 16; ++ni) {
        int n = ni * 16 + lr;
        float bv = bias[n];
        #pragma unroll
        for (int r = 0; r < 4; ++r) {
            int m = m0 + w * 16 + quad * 4 + r;
            if (m < M) {
                size_t idx = (size_t)m * 256 + n;
                float vl = acc[ni][r] + bv + res[idx];
                outf[idx] = vl;
                float li = POS ? (vl + pos[idx]) : vl;
                acc[ni][r] = li;
                s[r] += li;
                q[r] += li * li;
            }
        }
    }
    #pragma unroll
    for (int off = 1; off < 16; off <<= 1)
        #pragma unroll
        for (int r = 0; r < 4; ++r) {
            s[r] += __shfl_xor(s[r], off, 64);
            q[r] += __shfl_xor(q[r], off, 64);
        }
    float mean[4], inv[4];
    #pragma unroll
    for (int r = 0; r < 4; ++r) {
        mean[r] = s[r] * (1.0f / 256.0f);
        float var = q[r] * (1.0f / 256.0f) - mean[r] * mean[r];
        inv[r] = rsqrtf(var + 1e-5f);
    }
    #pragma unroll
    for (int ni = 0; ni < 16; ++ni) {
        int n = ni * 16 + lr;
        float g = gamma[n];
        float b = beta[n];
        #pragma unroll
        for (int r = 0; r < 4; ++r) {
            int m = m0 + w * 16 + quad * 4 + r;
            if (m < M)
                lnout[(size_t)m * 256 + n] = f2bf((acc[ni][r] - mean[r]) * inv[r] * g + b);
        }
    }
}

// ---------------------------------------------------------------------------
// off|wt GEMM (M=7200, N=96, K=256, grid (1,57)) with fused prep epilogue.
// ---------------------------------------------------------------------------
__global__ __launch_bounds__(256)
void gemm_offwt_prep(const unsigned short* __restrict__ A, const unsigned short* __restrict__ W,
                     const float* __restrict__ bias, const float* __restrict__ refp,
                     float4* __restrict__ sx, float4* __restrict__ sy, float4* __restrict__ sw)
{
    __shared__ unsigned short As[128 * 32];
    __shared__ unsigned short Bs[128 * 32];
    __shared__ float T[128][100];
    const int t    = threadIdx.x;
    const int m0   = blockIdx.y * 128;
    const int lane = t & 63;
    const int w    = t >> 6;
    const int wm   = (w >> 1) * 64;
    const int wn   = (w & 1) * 64;
    const int lr   = lane & 15;
    const int kq   = lane >> 4;
    const int M = M_, N = 96, K = 256;

    floatx4 acc[4][4];
    #pragma unroll
    for (int i = 0; i < 4; ++i)
        #pragma unroll
        for (int j = 0; j < 4; ++j) acc[i][j] = (floatx4){0.f, 0.f, 0.f, 0.f};

    const int sr = t >> 1;
    const int sc = (t & 1) * 2;
    const int gm = m0 + sr;
    const int gn = sr;
    const bool am = gm < M;
    const bool bn = gn < N;

    uint4 a0 = {0,0,0,0}, a1 = {0,0,0,0}, b0 = {0,0,0,0}, b1 = {0,0,0,0};
    if (am) {
        const uint4* src = (const uint4*)(A + (size_t)gm * K + sc * 8);
        a0 = src[0]; a1 = src[1];
    }
    if (bn) {
        const uint4* src = (const uint4*)(W + (size_t)gn * K + sc * 8);
        b0 = src[0]; b1 = src[1];
    }

    for (int k0 = 0; k0 < K; k0 += 32) {
        *(uint4*)&As[sr * 32 + ((sc    ) ^ (sr & 3)) * 8] = a0;
        *(uint4*)&As[sr * 32 + ((sc + 1) ^ (sr & 3)) * 8] = a1;
        *(uint4*)&Bs[sr * 32 + ((sc    ) ^ (sr & 3)) * 8] = b0;
        *(uint4*)&Bs[sr * 32 + ((sc + 1) ^ (sr & 3)) * 8] = b1;
        __syncthreads();

        if (k0 + 32 < K) {
            a0 = (uint4){0,0,0,0}; a1 = a0; b0 = a0; b1 = a0;
            if (am) {
                const uint4* src = (const uint4*)(A + (size_t)gm * K + (k0 + 32) + sc * 8);
                a0 = src[0]; a1 = src[1];
            }
            if (bn) {
                const uint4* src = (const uint4*)(W + (size_t)gn * K + (k0 + 32) + sc * 8);
                b0 = src[0]; b1 = src[1];
            }
        }

        short8 af[4], bfr[4];
        #pragma unroll
        for (int i = 0; i < 4; ++i) {
            int ra = wm + i * 16 + lr;
            af[i] = *(const short8*)&As[ra * 32 + (kq ^ (ra & 3)) * 8];
            int rb = wn + i * 16 + lr;
            bfr[i] = *(const short8*)&Bs[rb * 32 + (kq ^ (rb & 3)) * 8];
        }
        #pragma unroll
        for (int mi = 0; mi < 4; ++mi)
            #pragma unroll
            for (int ni = 0; ni < 4; ++ni)
                acc[mi][ni] = __builtin_amdgcn_mfma_f32_16x16x32_bf16(
                    af[mi], bfr[ni], acc[mi][ni], 0, 0, 0);
        __syncthreads();
    }

    const int rbase = kq * 4;
    #pragma unroll
    for (int ni = 0; ni < 4; ++ni) {
        int n = wn + ni * 16 + lr;
        if (n >= N) continue;
        float bv = bias[n];
        #pragma unroll
        for (int mi = 0; mi < 4; ++mi) {
            floatx4 c = acc[mi][ni];
            #pragma unroll
            for (int r = 0; r < 4; ++r)
                T[wm + mi * 16 + rbase + r][n] = c[r] + bv;
        }
    }
    __syncthreads();

    #pragma unroll
    for (int it = 0; it < 4; ++it) {
        int item = t + it * 256;
        int row  = item >> 3;
        int h    = item & 7;
        int gq   = m0 + row;
        if (gq >= M) continue;
        float rx = refp[gq * 2 + 0];
        float ry = refp[gq * 2 + 1];
        const float* orow = &T[row][h * 8];
        const float* wrow = &T[row][64 + h * 4];
        float gx[4], gy[4], wv[4];
        #pragma unroll
        for (int p = 0; p < 4; ++p) {
            float ox = tanhf(orow[p * 2 + 0]) * 0.2f;
            float oy = tanhf(orow[p * 2 + 1]) * 0.2f;
            gx[p] = (rx + ox) * (float)BEV_ - 0.5f;
            gy[p] = (ry + oy) * (float)BEV_ - 0.5f;
            wv[p] = wrow[p];
        }
        float mx = fmaxf(fmaxf(wv[0], wv[1]), fmaxf(wv[2], wv[3]));
        float e0 = expf(wv[0]-mx), e1 = expf(wv[1]-mx), e2 = expf(wv[2]-mx), e3 = expf(wv[3]-mx);
        float inv = 1.f / (e0 + e1 + e2 + e3);
        int idx = gq * 8 + h;
        sx[idx] = make_float4(gx[0], gx[1], gx[2], gx[3]);
        sy[idx] = make_float4(gy[0], gy[1], gy[2], gy[3]);
        sw[idx] = make_float4(e0*inv, e1*inv, e2*inv, e3*inv);
    }
}

// ---------------------------------------------------------------------------
// Flash self-attention. Grid (15, 64). 4 waves/block; wave owns 16 q-rows.
// ---------------------------------------------------------------------------
__global__ __launch_bounds__(256)
void flash_attn(const unsigned short* __restrict__ Qb, const unsigned short* __restrict__ Kb,
                const unsigned short* __restrict__ Vt, unsigned short* __restrict__ out)
{
    __shared__ unsigned short P_lds[4][2][16][72];
    const int bh   = blockIdx.y;
    const int b    = bh >> 3, h = bh & 7;
    const int q0   = blockIdx.x * 64;
    const int w    = threadIdx.x >> 6;
    const int lane = threadIdx.x & 63;
    const int lr   = lane & 15;
    const int quad = lane >> 4;

    const short8 qfrag = *(const short8*)(Qb + ((size_t)bh * NKPAD + q0 + w * 16 + lr) * 32 + quad * 8);

    floatx4 O0 = (floatx4){0.f,0.f,0.f,0.f};
    floatx4 O1 = (floatx4){0.f,0.f,0.f,0.f};
    float m_i[4] = {-INFINITY, -INFINITY, -INFINITY, -INFINITY};
    float l_i[4] = {0.f, 0.f, 0.f, 0.f};

    const unsigned short* kbase_p = Kb + (size_t)bh * NKPAD * 32;
    const unsigned short* vbase_p = Vt + (size_t)bh * 32 * NKPAD;

    short8 kf[4], kfn[4];
    #pragma unroll
    for (int ni = 0; ni < 4; ++ni)
        kf[ni] = *(const short8*)(kbase_p + (size_t)(ni * 16 + lr) * 32 + quad * 8);

    for (int kt = 0; kt < 15; ++kt) {
        const int kb = kt * 64;
        floatx4 S[4];
        #pragma unroll
        for (int ni = 0; ni < 4; ++ni)
            S[ni] = __builtin_amdgcn_mfma_f32_16x16x32_bf16(
                qfrag, kf[ni], (floatx4){0.f,0.f,0.f,0.f}, 0, 0, 0);
        if (kt < 14) {
            #pragma unroll
            for (int ni = 0; ni < 4; ++ni)
                kfn[ni] = *(const short8*)(kbase_p + (size_t)(kb + 64 + ni * 16 + lr) * 32 + quad * 8);
        }
        short8 vf0 = *(const short8*)(vbase_p + (size_t)(lr) * NKPAD + kb + quad * 8);
        short8 vf1 = *(const short8*)(vbase_p + (size_t)(lr) * NKPAD + kb + 32 + quad * 8);
        short8 vf2 = *(const short8*)(vbase_p + (size_t)(16 + lr) * NKPAD + kb + quad * 8);
        short8 vf3 = *(const short8*)(vbase_p + (size_t)(16 + lr) * NKPAD + kb + 32 + quad * 8);
        if (kt == 14) {
            #pragma unroll
            for (int ni = 0; ni < 4; ++ni) {
                int key = kb + ni * 16 + lr;
                if (key >= NQ_) S[ni] = (floatx4){-1e30f, -1e30f, -1e30f, -1e30f};
            }
        }
        float rowmax[4];
        #pragma unroll
        for (int r = 0; r < 4; ++r)
            rowmax[r] = fmaxf(fmaxf(S[0][r], S[1][r]), fmaxf(S[2][r], S[3][r]));
        #pragma unroll
        for (int off = 1; off < 16; off <<= 1)
            #pragma unroll
            for (int r = 0; r < 4; ++r)
                rowmax[r] = fmaxf(rowmax[r], __shfl_xor(rowmax[r], off, 64));
        float alpha[4], rs[4];
        #pragma unroll
        for (int r = 0; r < 4; ++r) {
            float mnew = fmaxf(m_i[r], rowmax[r]);
            alpha[r] = __expf(m_i[r] - mnew);
            m_i[r] = mnew;
            rs[r] = 0.f;
        }
        const int buf = kt & 1;
        #pragma unroll
        for (int ni = 0; ni < 4; ++ni) {
            #pragma unroll
            for (int r = 0; r < 4; ++r) {
                float p = __expf(S[ni][r] - m_i[r]);
                rs[r] += p;
                P_lds[w][buf][quad * 4 + r][ni * 16 + lr] = f2bf(p);
            }
        }
        #pragma unroll
        for (int off = 1; off < 16; off <<= 1)
            #pragma unroll
            for (int r = 0; r < 4; ++r)
                rs[r] += __shfl_xor(rs[r], off, 64);
        #pragma unroll
        for (int r = 0; r < 4; ++r) {
            l_i[r] = alpha[r] * l_i[r] + rs[r];
            O0[r] *= alpha[r];
            O1[r] *= alpha[r];
        }
        asm volatile("s_waitcnt lgkmcnt(0)" ::: "memory");
        short8 pf0 = *(const short8*)&P_lds[w][buf][lr][quad * 8];
        short8 pf1 = *(const short8*)&P_lds[w][buf][lr][32 + quad * 8];
        O0 = __builtin_amdgcn_mfma_f32_16x16x32_bf16(pf0, vf0, O0, 0, 0, 0);
        O0 = __builtin_amdgcn_mfma_f32_16x16x32_bf16(pf1, vf1, O0, 0, 0, 0);
        O1 = __builtin_amdgcn_mfma_f32_16x16x32_bf16(pf0, vf2, O1, 0, 0, 0);
        O1 = __builtin_amdgcn_mfma_f32_16x16x32_bf16(pf1, vf3, O1, 0, 0, 0);
        if (kt < 14) {
            #pragma unroll
            for (int ni = 0; ni < 4; ++ni) kf[ni] = kfn[ni];
        }
    }
    #pragma unroll
    for (int r = 0; r < 4; ++r) {
        int q = q0 + w * 16 + quad * 4 + r;
        if (q < NQ_) {
            float inv = 1.f / l_i[r];
            size_t base = ((size_t)(b * NQ_ + q)) * D_ + h * 32;
            out[base + lr]      = f2bf(O0[r] * inv);
            out[base + 16 + lr] = f2bf(O1[r] * inv);
        }
    }
}

// ---------------------------------------------------------------------------
// Bilinear sampler; bf16 out.
// ---------------------------------------------------------------------------
__global__ __launch_bounds__(256)
void sample_kernel(const float* __restrict__ mem,
                   const float4* __restrict__ sx, const float4* __restrict__ sy,
                   const float4* __restrict__ sw, unsigned short* __restrict__ fused)
{
    int tid = blockIdx.x * 256 + threadIdx.x;
    if (tid >= B_ * NQ_ * H_ * HD_) return;
    int d   = tid & 31;
    int bqh = tid >> 5;
    int h   = bqh & 7;
    int bq  = bqh >> 3;
    int b   = bq / NQ_;
    const float* mb = mem + (size_t)b * (BEV_ * BEV_) * D_ + h * HD_ + d;
    float4 X = sx[bqh], Y = sy[bqh], W = sw[bqh];
    float xs[4] = {X.x, X.y, X.z, X.w};
    float ys[4] = {Y.x, Y.y, Y.z, Y.w};
    float ws[4] = {W.x, W.y, W.z, W.w};
    float acc = 0.f;
    #pragma unroll
    for (int p = 0; p < 4; ++p) {
        float gx = xs[p], gy = ys[p];
        float x0f = floorf(gx), y0f = floorf(gy);
        int x0 = (int)x0f, y0 = (int)y0f;
        float wx1 = gx - x0f, wy1 = gy - y0f;
        float wx0 = 1.f - wx1, wy0 = 1.f - wy1;
        float s = 0.f;
        #pragma unroll
        for (int cy = 0; cy < 2; ++cy) {
            int yy = y0 + cy;
            if (yy < 0 || yy >= BEV_) continue;
            float wyv = cy ? wy1 : wy0;
            #pragma unroll
            for (int cx = 0; cx < 2; ++cx) {
                int xx = x0 + cx;
                if (xx < 0 || xx >= BEV_) continue;
                float wxv = cx ? wx1 : wx0;
                s += wyv * wxv * mb[((size_t)yy * BEV_ + xx) * D_];
            }
        }
        acc += ws[p] * s;
    }
    fused[(size_t)bq * D_ + h * HD_ + d] = f2bf(acc);
}

// ---------------------------------------------------------------------------
extern "C" void kernel_launch(void* const* d_in, const int* in_sizes, int n_in,
                              void* d_out, int out_size, void* d_ws, size_t ws_size,
                              hipStream_t stream) {
    const float* query     = (const float*)d_in[0];
    const float* memory    = (const float*)d_in[1];
    const float* refp      = (const float*)d_in[2];
    const float* query_pos = (const float*)d_in[3];
    const float* in_w  = (const float*)d_in[4];
    const float* in_b  = (const float*)d_in[5];
    const float* out_w = (const float*)d_in[6];
    const float* out_b = (const float*)d_in[7];
    const float* off_w = (const float*)d_in[8];
    const float* off_b = (const float*)d_in[9];
    const float* wt_w  = (const float*)d_in[10];
    const float* wt_b  = (const float*)d_in[11];
    const float* co_w  = (const float*)d_in[12];
    const float* co_b  = (const float*)d_in[13];
    const float* f_w1  = (const float*)d_in[14];
    const float* f_b1  = (const float*)d_in[15];
    const float* f_w2  = (const float*)d_in[16];
    const float* f_b2  = (const float*)d_in[17];
    const float* n1s = (const float*)d_in[18];
    const float* n1b = (const float*)d_in[19];
    const float* n2s = (const float*)d_in[20];
    const float* n2b = (const float*)d_in[21];
    const float* n3s = (const float*)d_in[22];
    const float* n3b = (const float*)d_in[23];
    float* outp = (float*)d_out;

    // workspace layout (bytes)
    char* w = (char*)d_ws;
    unsigned short* wb      = (unsigned short*)w;              // 1,228,800
    float*          bias_ow = (float*)(w + 1228800);           // 384 (pad)
    unsigned short* ln_bf   = (unsigned short*)(w + 1229184);  // 3,686,400
    float*          q1      = (float*)(w + 4915584);           // 7,372,800
    unsigned short* Qb      = (unsigned short*)(w + 23347584); // 3,932,160
    unsigned short* Kb      = (unsigned short*)(w + 27279744); // 3,932,160
    unsigned short* Vt      = (unsigned short*)(w + 31211904); // 3,932,160 -> end 35,144,064
    // overlays:
    float*          samp    = (float*)(w + 15053184);          // 2,764,800
    unsigned short* fuse_bf = (unsigned short*)(w + 17817984); // 3,686,400
    unsigned short* h1_bf   = (unsigned short*)(w + 12288384); // 7,372,800
    unsigned short* attn_bf = ln_bf;                           // reuse

    const unsigned short* wb_in  = wb;
    const unsigned short* wb_out = wb + 196608;
    const unsigned short* wb_ow  = wb + 262144;
    const unsigned short* wb_co  = wb + 286720;
    const unsigned short* wb_f1  = wb + 352256;
    const unsigned short* wb_f2  = wb + 483328;

    dim3 blk(256);
    const int M = M_;

    // 0. prologue: weights->bf16, flash pad zero, LN1
    prologue<<<dim3(5161), blk, 0, stream>>>(
        in_w, out_w, off_w, wt_w, co_w, f_w1, f_w2, off_b, wt_b, wb, bias_ow,
        Qb, Kb, Vt, query, query_pos, n1s, n1b, ln_bf);
    // 1. QKV GEMM with fused repack -> Qb/Kb/Vt
    gemm_mfma<0,0,1><<<dim3(6, 57), blk, 0, stream>>>(ln_bf, wb_in, in_b, nullptr,
                                                      nullptr, nullptr, Qb, Kb, Vt,
                                                      M, 768, 256);
    // 2. flash attention -> bf16 (into ln_bf region = attn_bf)
    flash_attn<<<dim3(15, 64), blk, 0, stream>>>(Qb, Kb, Vt, attn_bf);
    // 3. out-proj + residual(query) -> q1 fp32, fused LN2(q1+pos) -> ln_bf
    gemm_resln<1><<<dim3(57), dim3(512), 0, stream>>>(
        attn_bf, wb_out, out_b, query, query_pos, n2s, n2b, q1, ln_bf);
    // 4. merged off|wt projection + fused prep -> sx/sy/sw
    gemm_offwt_prep<<<dim3(1, 57), blk, 0, stream>>>(
        ln_bf, wb_ow, bias_ow, refp,
        (float4*)samp, (float4*)samp + 57600, (float4*)samp + 115200);
    // 5. bilinear sample + fuse -> bf16
    sample_kernel<<<dim3(B_ * NQ_ * H_ * HD_ / 256), blk, 0, stream>>>(
        memory, (const float4*)samp, (const float4*)samp + 57600,
        (const float4*)samp + 115200, fuse_bf);
    // 6. co-proj + residual(q1) -> d_out fp32, fused LN3 -> ln_bf
    gemm_resln<0><<<dim3(57), dim3(512), 0, stream>>>(
        fuse_bf, wb_co, co_b, q1, nullptr, n3s, n3b, outp, ln_bf);
    // 7. FFN1 + ReLU -> bf16 h1
    gemm_mfma<1,1,0><<<dim3(4, 57), blk, 0, stream>>>(ln_bf, wb_f1, f_b1, nullptr,
                                                      nullptr, h1_bf, nullptr, nullptr, nullptr,
                                                      M, 512, 256);
    // 8. FFN2 + residual(d_out) -> d_out
    gemm_mfma<0,0,0><<<dim3(2, 57), blk, 0, stream>>>(h1_bf, wb_f2, f_b2, outp,
                                                      outp, nullptr, nullptr, nullptr, nullptr,
                                                      M, 256, 512);
}